// Round 8
// baseline (6834.309 us; speedup 1.0000x reference)
//
#include <hip/hip_runtime.h>
#include <hip/hip_bf16.h>
#include <stdint.h>

// Problem dims
#define BB 256
#define TT 512
#define EE 128
#define HH 256
#define MM (TT*BB)       // 131072 rows total
#define CT 64            // timesteps per chunk
#define NCH (TT/CT)      // 8 chunks
#define CROWS (CT*BB)    // 16384 rows per chunk
// swizzled xp sizes (shorts)
#define RZ_DIR 8388608   // 64*16*8*64*16
#define RZ_TL  131072    // 16*8*64*16
#define N_DIR  4194304   // 64*16*8*64*8
#define N_TL   65536
// GRU dynamic LDS: swizzled n-gate weights [16g][8kt][64lane][8] + h dbuf [2][16*264]
#define WN_SH   65536                 // shorts (128 KB)
#define HBUF_SH (16*264)              // shorts per buffer
#define GRU_SMEM ((WN_SH + 2*HBUF_SH) * 2)   // bytes = 147968 (<= 160K)

typedef __attribute__((ext_vector_type(8))) short bf16x8;
typedef __attribute__((ext_vector_type(4))) short bf16x4;
typedef __attribute__((ext_vector_type(4))) float f32x4;

__device__ __forceinline__ float bf2f(unsigned short u){
  union { unsigned int i; float f; } v; v.i = ((unsigned int)u) << 16; return v.f;
}
__device__ __forceinline__ unsigned short f2bf(float f){
  union { float f; unsigned int i; } v; v.f = f;
  unsigned int u = v.i;
  unsigned int r = (u + 0x7FFFu + ((u >> 16) & 1u)) >> 16;
  return (unsigned short)r;
}
__device__ __forceinline__ float sigm(float x){ return 1.f / (1.f + __expf(-x)); }
__device__ __forceinline__ float tanh_f(float x){
  float e2 = __expf(2.f * x);
  return 1.f - 2.f / (e2 + 1.f);
}

// -------- sentinel --------
__global__ void k_sentinel(unsigned short* out, float v){ out[threadIdx.x] = f2bf(v); }

// -------- dtype probe: is this float tensor fp32 (vs bf16)? --------
__global__ void k_probe_f(const unsigned short* __restrict__ buf, int n,
                          unsigned* __restrict__ flagw){
  __shared__ int cnt;
  if (threadIdx.x == 0) cnt = 0;
  __syncthreads();
  int scanw = n < 4096 ? n : 4096;
  int bad = 0;
  for (int i = threadIdx.x; i < scanw; i += 256){
    unsigned short u = buf[i];
    unsigned e = (u >> 7) & 0xFF;
    if (u != 0 && (e < 0x60 || e == 0xFF)) bad++;
  }
  atomicAdd(&cnt, bad);
  __syncthreads();
  if (threadIdx.x == 0) *flagw = (cnt * 8 > scanw) ? 1u : 0u;
}

// -------- int width probe: int64 iff odd int32 words are (almost) all zero --------
__global__ void k_probe_i(const int* __restrict__ buf, int n, unsigned* __restrict__ flagw){
  __shared__ int cnt;
  if (threadIdx.x == 0) cnt = 0;
  __syncthreads();
  int scan = n < 1024 ? n : 1024;
  int nz = 0;
  for (int i = threadIdx.x; i < scan; i += 256)
    if ((i & 1) && buf[i] != 0) nz++;
  atomicAdd(&cnt, nz);
  __syncthreads();
  if (threadIdx.x == 0) *flagw = (cnt < 10) ? 1u : 0u;
}

// -------- convert a float tensor (fp32 or bf16 per flag) to bf16 dst --------
__global__ __launch_bounds__(256) void k_convert(const void* __restrict__ src, int n,
                                                 const unsigned* __restrict__ flagw,
                                                 unsigned short* __restrict__ dst){
  int fp32 = (int)*flagw;
  int i0 = blockIdx.x * 256 + threadIdx.x;
  int stride = gridDim.x * 256;
  if (fp32){
    const float* s = (const float*)src;
    for (int i = i0; i < n; i += stride) dst[i] = f2bf(s[i]);
  } else {
    const unsigned short* s = (const unsigned short*)src;
    for (int i = i0; i < n; i += stride) dst[i] = s[i];
  }
}

// -------- combined bias: cb[dir][n] = b_ih[dir][n] + (n < 512 ? b_hh[dir][n] : 0) --------
// NOTE: 768 is NOT a power of two -- must use %, not & (round-1 bug).
__global__ __launch_bounds__(256) void k_prep_bias(const unsigned short* __restrict__ bih,
                                                   const unsigned short* __restrict__ bhh,
                                                   unsigned short* __restrict__ cb){
  int i = blockIdx.x * 256 + threadIdx.x;   // 0..1535 (2 dirs x 768)
  if (i >= 1536) return;
  int n = i % 768;
  float v = bf2f(bih[i]);
  if (n < 512) v += bf2f(bhh[i]);
  cb[i] = f2bf(v);
}

// ---------------- embed: x[t*B+b][e] = embc[inputs[b][t]][e] (bf16) ----------------
__global__ __launch_bounds__(256) void k_embed(const unsigned short* __restrict__ embc,
                                               const void* __restrict__ inputs,
                                               const unsigned* __restrict__ i64f,
                                               unsigned short* __restrict__ x){
  int c = blockIdx.x * 256 + threadIdx.x;  // 16B chunk id; total = MM*16
  int e8 = (c & 15) * 8;
  int tb = c >> 4;
  int t = tb >> 8;
  int b = tb & 255;
  long k = (long)b * TT + t;
  int idx = (*i64f) ? ((const int*)inputs)[k * 2] : ((const int*)inputs)[k];
  idx = idx < 0 ? 0 : (idx > 64 ? 64 : idx);
  *(bf16x8*)(x + (long)tb * EE + e8) = *(const bf16x8*)(embc + (long)idx * EE + e8);
}

// ------- chunk xp GEMM, both dirs (grid.z), epilogue writes GRU-swizzled xp -------
template<int K>
__global__ __launch_bounds__(256) void k_gemm_chunk(const unsigned short* __restrict__ A,
                                                    const unsigned short* __restrict__ W,
                                                    const unsigned short* __restrict__ bias,
                                                    unsigned short* __restrict__ xprz,
                                                    unsigned short* __restrict__ xpn,
                                                    int t0f, int t0b){
  __shared__ __align__(16) unsigned short As[128 * 72];
  __shared__ __align__(16) unsigned short Bs[128 * 72];
  int dir = blockIdx.z;
  const unsigned short* Ad = A + (long)(dir ? t0b : t0f) * 256 * K;
  const unsigned short* Wd = W + (long)dir * 768 * K;
  const unsigned short* bd = bias + dir * 768;
  unsigned short* rzd = xprz + (long)dir * RZ_DIR;
  unsigned short* nd  = xpn  + (long)dir * N_DIR;

  int tid = threadIdx.x;
  long m0 = (long)blockIdx.x * 128;
  int  n0 = blockIdx.y * 128;
  int wave = tid >> 6, lane = tid & 63;
  int wm = (wave & 1) * 64, wn = (wave >> 1) * 64;
  int ln16 = lane & 15, quad = lane >> 4;
  f32x4 acc[4][4];
  #pragma unroll
  for (int i = 0; i < 4; i++)
    #pragma unroll
    for (int j = 0; j < 4; j++) acc[i][j] = (f32x4){0.f,0.f,0.f,0.f};

  for (int k0 = 0; k0 < K; k0 += 64){
    #pragma unroll
    for (int i = 0; i < 4; i++){
      int c = tid + 256 * i;        // 1024 chunks of 8 bf16
      int row = c >> 3, koff = (c & 7) * 8;
      *(bf16x8*)&As[row * 72 + koff] = *(const bf16x8*)&Ad[(m0 + row) * K + k0 + koff];
      *(bf16x8*)&Bs[row * 72 + koff] = *(const bf16x8*)&Wd[(long)(n0 + row) * K + k0 + koff];
    }
    __syncthreads();
    #pragma unroll
    for (int kk = 0; kk < 64; kk += 32){
      bf16x8 af[4], bfr[4];
      #pragma unroll
      for (int mi = 0; mi < 4; mi++) af[mi]  = *(bf16x8*)&As[(wm + mi*16 + ln16) * 72 + kk + quad*8];
      #pragma unroll
      for (int nj = 0; nj < 4; nj++) bfr[nj] = *(bf16x8*)&Bs[(wn + nj*16 + ln16) * 72 + kk + quad*8];
      #pragma unroll
      for (int mi = 0; mi < 4; mi++)
        #pragma unroll
        for (int nj = 0; nj < 4; nj++)
          acc[mi][nj] = __builtin_amdgcn_mfma_f32_16x16x32_bf16(af[mi], bfr[nj], acc[mi][nj], 0, 0, 0);
    }
    __syncthreads();
  }
  // swizzled epilogue
  #pragma unroll
  for (int mi = 0; mi < 4; mi++)
    #pragma unroll
    for (int nj = 0; nj < 4; nj++){
      int n = n0 + wn + nj*16 + ln16;       // 0..767 within dir
      int g = n >> 8, c = n & 255;
      int w = c >> 5, ii = (c >> 4) & 1;
      float bv = bf2f(bd[n]);
      #pragma unroll
      for (int r = 0; r < 4; r++){
        long m = m0 + wm + mi*16 + quad*4 + r;
        int tl = (int)(m >> 8);
        int bgx = ((int)m & 255) >> 4;      // m&15 == quad*4+r
        long rec = (((long)tl*16 + bgx)*8 + w)*64 + quad*16 + ln16;
        unsigned short val = f2bf(acc[mi][nj][r] + bv);
        if (g < 2) rzd[rec*16 + ii*8 + g*4 + r] = val;
        else       nd [rec*8  + ii*4 + r]       = val;
      }
    }
}

// ---------------- GRU recurrence over one 64-step chunk, both dirs ----------------
// grid = 32 blocks (dir = blk>>4, batch group of 16 = blk&15), 1024 threads (16 waves).
// ROUND-7 POST-MORTEM: doubling waves (8->16) changed NOTHING (194->196us) -- the
// per-step cost is a fixed serial latency all variants share: __syncthreads() emits
// `s_waitcnt vmcnt(0) lgkmcnt(0)` before s_barrier, draining the 4 global output
// stores AND the next-step xp prefetch (~900cyc HBM round trip, 57% L3-miss) into
// the 64-step serial chain EVERY step.
// THIS VERSION (AITER/HK counted-wait technique):
//  - raw `s_waitcnt lgkmcnt(0)` + __builtin_amdgcn_s_barrier() + sched_barrier(0):
//    the barrier only needs LDS ordering (h double-buffer); stores are never read
//    in-kernel and xp loads feed only the issuing wave's registers -> vmcnt may
//    legally stay outstanding across the barrier.
//  - xp prefetch depth 2 via manual 2x-unroll with A/B register sets (no
//    cross-iteration register copies -> no artificial vmcnt waits): load-to-use
//    distance ~2 steps, covering the HBM miss latency.
// Retained from rounds 6/7: laundered r,z weights in regs (64 VGPR), n-gate
// weights in LDS fragment-major conflict-free layout, 16 waves / 4 per SIMD.
__global__ __attribute__((amdgpu_flat_work_group_size(1024, 1024), amdgpu_waves_per_eu(4, 4)))
void k_gru_chunk(const unsigned short* __restrict__ xprz,
                 const unsigned short* __restrict__ xpn,
                 const unsigned short* __restrict__ whh,
                 const unsigned short* __restrict__ bhh,
                 float* __restrict__ hstate,  // [2][256][256]
                 unsigned short* __restrict__ outf,
                 unsigned short* __restrict__ outb,
                 int out_full, int t0f, int t0b){
  extern __shared__ __align__(16) unsigned short smem[];   // [WN_SH] + [2][HBUF_SH]
  unsigned short* wn_lds = smem;
  unsigned short* hbuf   = smem + WN_SH;

  int tid = threadIdx.x;
  int dir = blockIdx.x >> 4;
  int bg  = blockIdx.x & 15;
  int b0  = bg * 16;
  int wave = tid >> 6, lane = tid & 63;
  int ln16 = lane & 15, quad = lane >> 4;
  int c = wave*16 + ln16;                      // this thread's output column, 0..255
  unsigned short* outp = dir ? outb : outf;
  int t0 = dir ? t0b : t0f;

  const unsigned short* rzbase = xprz + (long)dir * RZ_DIR
                               + ((long)(bg*8 + (wave>>1))*64 + lane) * 16 + (wave&1)*8;
  const unsigned short* nbase  = xpn  + (long)dir * N_DIR
                               + ((long)(bg*8 + (wave>>1))*64 + lane) * 8  + (wave&1)*4;

  // stage n-gate weights into LDS, fragment-major (conflict-free ds_read_b128)
  for (int v = tid; v < 256*32; v += 1024){
    int cc = v >> 5, j = v & 31;
    int g = cc >> 4, l16 = cc & 15;
    int kt = j >> 2, qd = j & 3;
    *(bf16x8*)&wn_lds[(((g*8 + kt)*64) + qd*16 + l16) * 8] =
      *(const bf16x8*)&whh[((long)(dir*768 + 512 + cc))*256 + j*8];
  }

  // r,z weight fragments register-resident (64 VGPR), laundered
  bf16x8 wr[8], wz[8];
  {
    const unsigned short* Wb = whh + ((long)(dir*768 + c)) * 256 + quad*8;
    #pragma unroll
    for (int kt = 0; kt < 8; kt++){
      wr[kt] = *(const bf16x8*)(Wb + kt*32);
      wz[kt] = *(const bf16x8*)(Wb + 256*256 + kt*32);
      asm volatile("" : "+v"(wr[kt]), "+v"(wz[kt]));
    }
  }

  // carried state -> regs + LDS buffer 0
  float h_old[4];
  #pragma unroll
  for (int r = 0; r < 4; r++){
    int b = quad*4 + r;
    float hv = hstate[((long)dir*256 + b0 + b)*256 + c];
    h_old[r] = hv;
    hbuf[b * 264 + c] = f2bf(hv);
  }
  float bh_n = bf2f(bhh[dir*768 + 512 + c]);

  int wnbase = wave*4096 + lane*8;             // shorts

  // time index of logical step k
  #define TIDX(k) (dir ? (CT-1-(k)) : (k))

  // prefetch depth 2: A holds step ss, B holds step ss+1
  bf16x8 rzA = *(const bf16x8*)(rzbase + (long)TIDX(0)*RZ_TL);
  bf16x4 nA  = *(const bf16x4*)(nbase  + (long)TIDX(0)*N_TL);
  bf16x8 rzB = *(const bf16x8*)(rzbase + (long)TIDX(1)*RZ_TL);
  bf16x4 nB  = *(const bf16x4*)(nbase  + (long)TIDX(1)*N_TL);

  asm volatile("s_waitcnt lgkmcnt(0)" ::: "memory");
  __builtin_amdgcn_s_barrier();
  __builtin_amdgcn_sched_barrier(0);

  int p = 0;

  auto gru_step = [&](int ss, bf16x8& xrz, bf16x4& xn4){
    unsigned short* hb_cur = hbuf + p*HBUF_SH;
    unsigned short* hb_nxt = hbuf + (1-p)*HBUF_SH;

    f32x4 ar = (f32x4){0.f,0.f,0.f,0.f};
    f32x4 az = (f32x4){0.f,0.f,0.f,0.f};
    f32x4 an = (f32x4){0.f,0.f,0.f,0.f};

    // 2-deep pipelined LDS reads: h A-fragment + conflict-free n-gate B-fragment
    bf16x8 afb[2], wnb[2];
    afb[0] = *(bf16x8*)&hb_cur[ln16*264 + quad*8];
    wnb[0] = *(bf16x8*)&wn_lds[wnbase];
    #pragma unroll
    for (int kt = 0; kt < 8; kt++){
      int cur = kt & 1, nxt = cur ^ 1;
      if (kt < 7){
        afb[nxt] = *(bf16x8*)&hb_cur[ln16*264 + (kt+1)*32 + quad*8];
        wnb[nxt] = *(bf16x8*)&wn_lds[wnbase + (kt+1)*512];
      }
      ar = __builtin_amdgcn_mfma_f32_16x16x32_bf16(afb[cur], wr[kt], ar, 0, 0, 0);
      az = __builtin_amdgcn_mfma_f32_16x16x32_bf16(afb[cur], wz[kt], az, 0, 0, 0);
      an = __builtin_amdgcn_mfma_f32_16x16x32_bf16(afb[cur], wnb[cur], an, 0, 0, 0);
    }

    int tcur = TIDX(ss);
    #pragma unroll
    for (int r = 0; r < 4; r++){
      float xr = bf2f((unsigned short)xrz[r]);
      float xz = bf2f((unsigned short)xrz[4+r]);
      float xn = bf2f((unsigned short)xn4[r]);
      float rg = sigm(xr + ar[r]);                    // b_hh_r already in xr
      float zg = sigm(xz + az[r]);                    // b_hh_z already in xz
      float ng = tanh_f(xn + rg * (an[r] + bh_n));
      float hnew = (1.f - zg) * ng + zg * h_old[r];
      h_old[r] = hnew;
      unsigned short hb = f2bf(hnew);
      int b = b0 + quad*4 + r;
      hb_nxt[(quad*4 + r) * 264 + c] = hb;
      long oidx = out_full ? (((long)(t0 + tcur) * 256 + b) * 512 + dir*256 + c)
                           : (((long)tcur * 256 + b) * 256 + c);
      outp[oidx] = hb;
    }

    // re-arm this register set for step ss+2 (clamped at tail; value unused then)
    int kpf = (ss + 2 < CT) ? (ss + 2) : ss;
    int tpf = TIDX(kpf);
    xrz = *(const bf16x8*)(rzbase + (long)tpf*RZ_TL);
    xn4 = *(const bf16x4*)(nbase  + (long)tpf*N_TL);

    // LDS-only barrier: global stores/loads stay in flight across it
    asm volatile("s_waitcnt lgkmcnt(0)" ::: "memory");
    __builtin_amdgcn_s_barrier();
    __builtin_amdgcn_sched_barrier(0);
    p ^= 1;
  };

  for (int ss = 0; ss < CT; ss += 2){
    gru_step(ss,     rzA, nA);
    gru_step(ss + 1, rzB, nB);
  }
  #undef TIDX

  #pragma unroll
  for (int r = 0; r < 4; r++)
    hstate[((long)dir*256 + b0 + quad*4 + r)*256 + c] = h_old[r];
}

// ------- FC1 per-chunk split-K, both dirs (grid.y): fc1acc += h2[dir] @ W1_dir-slice -------
__global__ __launch_bounds__(256) void k_fc1_chunk(const unsigned short* __restrict__ h2,
                                                   const void* __restrict__ W1,
                                                   const unsigned* __restrict__ w1f,
                                                   int t0f, int t0b,
                                                   float* __restrict__ fc1acc){
  int dir = blockIdx.y;
  const unsigned short* h2d = h2 + (long)dir * CROWS * 256;
  int t0 = dir ? t0b : t0f;
  int dircol = dir * 256;
  int mb = blockIdx.x & 3, kb = blockIdx.x >> 2;
  int wave = threadIdx.x >> 6, lane = threadIdx.x & 63;
  int ln16 = lane & 15, quad = lane >> 4;
  int w1fp32 = (int)*w1f;
  f32x4 acc[8];
  #pragma unroll
  for (int nt = 0; nt < 8; nt++) acc[nt] = (f32x4){0.f,0.f,0.f,0.f};

  for (int tt = 0; tt < 4; tt++){
    int tl = kb*4 + tt;
    const unsigned short* A = h2d + ((long)tl * 256 + mb*64 + wave*16) * 256;
    long bbase = (long)(t0 + tl) * 512 + dircol;
    #pragma unroll
    for (int kt = 0; kt < 8; kt++){
      bf16x8 af = *(const bf16x8*)(A + (long)ln16*256 + kt*32 + quad*8);
      #pragma unroll
      for (int nt = 0; nt < 8; nt++){
        long off = bbase + (long)(nt*16 + ln16)*262144 + kt*32 + quad*8;
        bf16x8 bfr;
        if (w1fp32){
          const float* pp = (const float*)W1 + off;
          #pragma unroll
          for (int j = 0; j < 8; j++) bfr[j] = (short)f2bf(pp[j]);
        } else {
          bfr = *(const bf16x8*)((const unsigned short*)W1 + off);
        }
        acc[nt] = __builtin_amdgcn_mfma_f32_16x16x32_bf16(af, bfr, acc[nt], 0, 0, 0);
      }
    }
  }
  #pragma unroll
  for (int nt = 0; nt < 8; nt++)
    #pragma unroll
    for (int r = 0; r < 4; r++){
      int m = mb*64 + wave*16 + quad*4 + r;
      int n = nt*16 + ln16;
      atomicAdd(&fc1acc[m*128 + n], acc[nt][r]);
    }
}

// ------- final: leaky_relu(fc1acc + b1) @ W2 + b2 -> sigmoid -------
__global__ __launch_bounds__(256) void k_fc2(const float* __restrict__ fc1acc,
                                             const unsigned short* __restrict__ b1,
                                             const unsigned short* __restrict__ W2,
                                             const unsigned short* __restrict__ b2,
                                             const unsigned* __restrict__ flags,
                                             void* __restrict__ out){
  int b = threadIdx.x;
  float s = bf2f(b2[0]);
  for (int j = 0; j < 128; j++){
    float v = fc1acc[b*128 + j] + bf2f(b1[j]);
    v = v > 0.f ? v : 0.01f * v;
    s += v * bf2f(W2[j]);
  }
  float r = sigm(s);
  if (flags[1]) ((float*)out)[b] = r;          // fp32 world -> fp32 output
  else          ((unsigned short*)out)[b] = f2bf(r);
}

extern "C" void kernel_launch(void* const* d_in, const int* in_sizes, int n_in,
                              void* d_out, int out_size, void* d_ws, size_t ws_size,
                              hipStream_t stream) {
  const void* inp  = d_in[0];
  const void* emb  = d_in[1];
  const void* wih0 = d_in[2];
  const void* whh0 = d_in[3];
  const void* bih0 = d_in[4];
  const void* bhh0 = d_in[5];
  const void* wih1 = d_in[6];
  const void* whh1 = d_in[7];
  const void* bih1 = d_in[8];
  const void* bhh1 = d_in[9];
  const void* W1   = d_in[10];
  const void* b1   = d_in[11];
  const void* W2   = d_in[12];
  const void* b2   = d_in[13];
  unsigned short* out = (unsigned short*)d_out;

  const int expect[14] = {131072, 8320, 196608, 393216, 1536, 1536,
                          786432, 393216, 1536, 1536, 33554432, 128, 128, 1};
  for (int i = 0; i < 14 && i < n_in; i++){
    if (in_sizes[i] != expect[i]){
      k_sentinel<<<1, 256, 0, stream>>>(out, 4.0f * (600.0f + i));
      return;
    }
  }

  // dynamic LDS attr (idempotent host-side attr, not a stream op; 145 KB)
  static int smem_set = 0;
  if (!smem_set){
    hipFuncSetAttribute((const void*)k_gru_chunk,
                        hipFuncAttributeMaxDynamicSharedMemorySize, GRU_SMEM);
    smem_set = 1;
  }

  // workspace layout (bytes)
  const size_t OFF_X    = 0;                       // x    [131072*128] bf16
  const size_t OFF_H1   = 33554432ul;              // h1   [131072*512] bf16
  const size_t OFF_XPRZ = 167772160ul;             // xprz [2][RZ_DIR] bf16 (33.6 MB)
  const size_t OFF_XPN  = 201326592ul;             // xpn  [2][N_DIR]  bf16 (16.8 MB)
  const size_t OFF_H2   = 218103808ul;             // h2   [2][16384*256] bf16 (16.8 MB)
  const size_t OFF_ST   = 234881024ul;             // hstate [2*256*256] f32
  const size_t OFF_FC   = 235405312ul;             // fc1acc [256*128] f32
  const size_t OFF_FLAG = 235536384ul;             // 16 flag words
  const size_t OFF_P    = 235536448ul;             // converted bf16 params (~3.6 MB)
  unsigned short* P;
  const size_t PO_EMB  = 0;        // 8320
  const size_t PO_WIH0 = 8320;     // 196608
  const size_t PO_WHH0 = 204928;   // 393216
  const size_t PO_BIH0 = 598144;   // 1536
  const size_t PO_BHH0 = 599680;   // 1536
  const size_t PO_WIH1 = 601216;   // 786432
  const size_t PO_WHH1 = 1387648;  // 393216
  const size_t PO_BIH1 = 1780864;  // 1536
  const size_t PO_BHH1 = 1782400;  // 1536
  const size_t PO_B1   = 1783936;  // 128
  const size_t PO_W2   = 1784064;  // 128
  const size_t PO_B2   = 1784192;  // 1 (+pad)
  const size_t PO_CB0  = 1784200;  // combined bias layer0 [2*768]
  const size_t PO_CB1  = 1785736;  // combined bias layer1 [2*768]
  const size_t NEED    = OFF_P + 2*(1785736ul + 1536ul);

  if (ws_size < NEED) {
    k_sentinel<<<1, 256, 0, stream>>>(out, (float)(ws_size >> 20));
    return;
  }

  char* ws = (char*)d_ws;
  unsigned short* x    = (unsigned short*)(ws + OFF_X);
  unsigned short* h1   = (unsigned short*)(ws + OFF_H1);
  unsigned short* xprz = (unsigned short*)(ws + OFF_XPRZ);
  unsigned short* xpn  = (unsigned short*)(ws + OFF_XPN);
  unsigned short* h2   = (unsigned short*)(ws + OFF_H2);
  unsigned short* h2b  = h2 + (long)CROWS*256;
  float*          hst  = (float*)(ws + OFF_ST);
  float*          fc1a = (float*)(ws + OFF_FC);
  unsigned*       flg  = (unsigned*)(ws + OFF_FLAG);
  P = (unsigned short*)(ws + OFF_P);

  hipMemsetAsync(flg, 0, 64, stream);

  // ---- dtype probes ----
  k_probe_f<<<1,256,0,stream>>>((const unsigned short*)emb,  8320,     flg+1);
  k_probe_f<<<1,256,0,stream>>>((const unsigned short*)wih0, 196608,   flg+2);
  k_probe_f<<<1,256,0,stream>>>((const unsigned short*)whh0, 393216,   flg+3);
  k_probe_f<<<1,256,0,stream>>>((const unsigned short*)bih0, 1536,     flg+4);
  k_probe_f<<<1,256,0,stream>>>((const unsigned short*)bhh0, 1536,     flg+5);
  k_probe_f<<<1,256,0,stream>>>((const unsigned short*)wih1, 786432,   flg+6);
  k_probe_f<<<1,256,0,stream>>>((const unsigned short*)whh1, 393216,   flg+7);
  k_probe_f<<<1,256,0,stream>>>((const unsigned short*)bih1, 1536,     flg+8);
  k_probe_f<<<1,256,0,stream>>>((const unsigned short*)bhh1, 1536,     flg+9);
  k_probe_f<<<1,256,0,stream>>>((const unsigned short*)b1,   128,      flg+10);
  k_probe_f<<<1,256,0,stream>>>((const unsigned short*)W2,   128,      flg+11);
  k_probe_f<<<1,256,0,stream>>>((const unsigned short*)b2,   1,        flg+12);
  k_probe_f<<<1,256,0,stream>>>((const unsigned short*)W1,   33554432, flg+13);
  k_probe_i<<<1,256,0,stream>>>((const int*)inp, 131072, flg+14);

  // ---- convert params to bf16 ----
  k_convert<<<64,256,0,stream>>>(emb,  8320,   flg+1,  P+PO_EMB);
  k_convert<<<64,256,0,stream>>>(wih0, 196608, flg+2,  P+PO_WIH0);
  k_convert<<<64,256,0,stream>>>(whh0, 393216, flg+3,  P+PO_WHH0);
  k_convert<<<8, 256,0,stream>>>(bih0, 1536,   flg+4,  P+PO_BIH0);
  k_convert<<<8, 256,0,stream>>>(bhh0, 1536,   flg+5,  P+PO_BHH0);
  k_convert<<<64,256,0,stream>>>(wih1, 786432, flg+6,  P+PO_WIH1);
  k_convert<<<64,256,0,stream>>>(whh1, 393216, flg+7,  P+PO_WHH1);
  k_convert<<<8, 256,0,stream>>>(bih1, 1536,   flg+8,  P+PO_BIH1);
  k_convert<<<8, 256,0,stream>>>(bhh1, 1536,   flg+9,  P+PO_BHH1);
  k_convert<<<1, 256,0,stream>>>(b1,   128,    flg+10, P+PO_B1);
  k_convert<<<1, 256,0,stream>>>(W2,   128,    flg+11, P+PO_W2);
  k_convert<<<1, 256,0,stream>>>(b2,   1,      flg+12, P+PO_B2);

  // ---- combined biases (b_ih + b_hh for r,z gates) ----
  k_prep_bias<<<6,256,0,stream>>>(P+PO_BIH0, P+PO_BHH0, P+PO_CB0);
  k_prep_bias<<<6,256,0,stream>>>(P+PO_BIH1, P+PO_BHH1, P+PO_CB1);

  k_embed<<<MM*16/256, 256, 0, stream>>>(P+PO_EMB, inp, flg+14, x);

  // ---- layer 0 ----
  hipMemsetAsync(hst, 0, 2*256*256*sizeof(float), stream);
  for (int c = 0; c < NCH; c++){
    int t0f = c * CT, t0b = (NCH - 1 - c) * CT;
    k_gemm_chunk<128><<<dim3(CROWS/128, 6, 2), 256, 0, stream>>>(x, P+PO_WIH0, P+PO_CB0, xprz, xpn, t0f, t0b);
    k_gru_chunk<<<32, 1024, GRU_SMEM, stream>>>(xprz, xpn, P+PO_WHH0, P+PO_BHH0, hst, h1, h1, 1, t0f, t0b);
  }

  // ---- layer 1 (+ fused FC1 accumulation) ----
  hipMemsetAsync(hst, 0, 2*256*256*sizeof(float), stream);
  hipMemsetAsync(fc1a, 0, 256*128*sizeof(float), stream);
  for (int c = 0; c < NCH; c++){
    int t0f = c * CT, t0b = (NCH - 1 - c) * CT;
    k_gemm_chunk<512><<<dim3(CROWS/128, 6, 2), 256, 0, stream>>>(h1, P+PO_WIH1, P+PO_CB1, xprz, xpn, t0f, t0b);
    k_gru_chunk<<<32, 1024, GRU_SMEM, stream>>>(xprz, xpn, P+PO_WHH1, P+PO_BHH1, hst, h2, h2b, 0, t0f, t0b);
    k_fc1_chunk<<<dim3(64, 2), 256, 0, stream>>>(h2, W1, flg+13, t0f, t0b, fc1a);
  }

  k_fc2<<<1, 256, 0, stream>>>(fc1a, P+PO_B1, P+PO_W2, P+PO_B2, flg, d_out);
}

// Round 9
// 6831.539 us; speedup vs baseline: 1.0004x; 1.0004x over previous
//
#include <hip/hip_runtime.h>
#include <hip/hip_bf16.h>
#include <stdint.h>

// Problem dims
#define BB 256
#define TT 512
#define EE 128
#define HH 256
#define MM (TT*BB)       // 131072 rows total
#define CT 64            // timesteps per chunk
#define NCH (TT/CT)      // 8 chunks
#define CROWS (CT*BB)    // 16384 rows per chunk
// swizzled xp sizes (shorts)
#define RZ_DIR 8388608   // 64*16*8*64*16
#define RZ_TL  131072    // 16*8*64*16
#define N_DIR  4194304   // 64*16*8*64*8
#define N_TL   65536
// GRU dynamic LDS: h double buffer only (ALL weights register-resident now)
#define HBUF_SH (16*264)              // shorts per buffer
#define GRU_SMEM (2*HBUF_SH*2)        // bytes = 16896

typedef __attribute__((ext_vector_type(8))) short bf16x8;
typedef __attribute__((ext_vector_type(4))) float f32x4;

__device__ __forceinline__ float bf2f(unsigned short u){
  union { unsigned int i; float f; } v; v.i = ((unsigned int)u) << 16; return v.f;
}
__device__ __forceinline__ unsigned short f2bf(float f){
  union { float f; unsigned int i; } v; v.f = f;
  unsigned int u = v.i;
  unsigned int r = (u + 0x7FFFu + ((u >> 16) & 1u)) >> 16;
  return (unsigned short)r;
}
__device__ __forceinline__ float sigm(float x){ return 1.f / (1.f + __expf(-x)); }
__device__ __forceinline__ float tanh_f(float x){
  float e2 = __expf(2.f * x);
  return 1.f - 2.f / (e2 + 1.f);
}

// -------- sentinel --------
__global__ void k_sentinel(unsigned short* out, float v){ out[threadIdx.x] = f2bf(v); }

// -------- dtype probe: is this float tensor fp32 (vs bf16)? --------
__global__ void k_probe_f(const unsigned short* __restrict__ buf, int n,
                          unsigned* __restrict__ flagw){
  __shared__ int cnt;
  if (threadIdx.x == 0) cnt = 0;
  __syncthreads();
  int scanw = n < 4096 ? n : 4096;
  int bad = 0;
  for (int i = threadIdx.x; i < scanw; i += 256){
    unsigned short u = buf[i];
    unsigned e = (u >> 7) & 0xFF;
    if (u != 0 && (e < 0x60 || e == 0xFF)) bad++;
  }
  atomicAdd(&cnt, bad);
  __syncthreads();
  if (threadIdx.x == 0) *flagw = (cnt * 8 > scanw) ? 1u : 0u;
}

// -------- int width probe: int64 iff odd int32 words are (almost) all zero --------
__global__ void k_probe_i(const int* __restrict__ buf, int n, unsigned* __restrict__ flagw){
  __shared__ int cnt;
  if (threadIdx.x == 0) cnt = 0;
  __syncthreads();
  int scan = n < 1024 ? n : 1024;
  int nz = 0;
  for (int i = threadIdx.x; i < scan; i += 256)
    if ((i & 1) && buf[i] != 0) nz++;
  atomicAdd(&cnt, nz);
  __syncthreads();
  if (threadIdx.x == 0) *flagw = (cnt < 10) ? 1u : 0u;
}

// -------- convert a float tensor (fp32 or bf16 per flag) to bf16 dst --------
__global__ __launch_bounds__(256) void k_convert(const void* __restrict__ src, int n,
                                                 const unsigned* __restrict__ flagw,
                                                 unsigned short* __restrict__ dst){
  int fp32 = (int)*flagw;
  int i0 = blockIdx.x * 256 + threadIdx.x;
  int stride = gridDim.x * 256;
  if (fp32){
    const float* s = (const float*)src;
    for (int i = i0; i < n; i += stride) dst[i] = f2bf(s[i]);
  } else {
    const unsigned short* s = (const unsigned short*)src;
    for (int i = i0; i < n; i += stride) dst[i] = s[i];
  }
}

// -------- combined bias: cb[dir][n] = b_ih[dir][n] + (n < 512 ? b_hh[dir][n] : 0) --------
// NOTE: 768 is NOT a power of two -- must use %, not & (round-1 bug).
__global__ __launch_bounds__(256) void k_prep_bias(const unsigned short* __restrict__ bih,
                                                   const unsigned short* __restrict__ bhh,
                                                   unsigned short* __restrict__ cb){
  int i = blockIdx.x * 256 + threadIdx.x;   // 0..1535 (2 dirs x 768)
  if (i >= 1536) return;
  int n = i % 768;
  float v = bf2f(bih[i]);
  if (n < 512) v += bf2f(bhh[i]);
  cb[i] = f2bf(v);
}

// ---------------- embed: x[t*B+b][e] = embc[inputs[b][t]][e] (bf16) ----------------
__global__ __launch_bounds__(256) void k_embed(const unsigned short* __restrict__ embc,
                                               const void* __restrict__ inputs,
                                               const unsigned* __restrict__ i64f,
                                               unsigned short* __restrict__ x){
  int c = blockIdx.x * 256 + threadIdx.x;  // 16B chunk id; total = MM*16
  int e8 = (c & 15) * 8;
  int tb = c >> 4;
  int t = tb >> 8;
  int b = tb & 255;
  long k = (long)b * TT + t;
  int idx = (*i64f) ? ((const int*)inputs)[k * 2] : ((const int*)inputs)[k];
  idx = idx < 0 ? 0 : (idx > 64 ? 64 : idx);
  *(bf16x8*)(x + (long)tb * EE + e8) = *(const bf16x8*)(embc + (long)idx * EE + e8);
}

// ------- chunk xp GEMM, both dirs (grid.z), epilogue writes GRU-swizzled xp -------
template<int K>
__global__ __launch_bounds__(256) void k_gemm_chunk(const unsigned short* __restrict__ A,
                                                    const unsigned short* __restrict__ W,
                                                    const unsigned short* __restrict__ bias,
                                                    unsigned short* __restrict__ xprz,
                                                    unsigned short* __restrict__ xpn,
                                                    int t0f, int t0b){
  __shared__ __align__(16) unsigned short As[128 * 72];
  __shared__ __align__(16) unsigned short Bs[128 * 72];
  int dir = blockIdx.z;
  const unsigned short* Ad = A + (long)(dir ? t0b : t0f) * 256 * K;
  const unsigned short* Wd = W + (long)dir * 768 * K;
  const unsigned short* bd = bias + dir * 768;
  unsigned short* rzd = xprz + (long)dir * RZ_DIR;
  unsigned short* nd  = xpn  + (long)dir * N_DIR;

  int tid = threadIdx.x;
  long m0 = (long)blockIdx.x * 128;
  int  n0 = blockIdx.y * 128;
  int wave = tid >> 6, lane = tid & 63;
  int wm = (wave & 1) * 64, wn = (wave >> 1) * 64;
  int ln16 = lane & 15, quad = lane >> 4;
  f32x4 acc[4][4];
  #pragma unroll
  for (int i = 0; i < 4; i++)
    #pragma unroll
    for (int j = 0; j < 4; j++) acc[i][j] = (f32x4){0.f,0.f,0.f,0.f};

  for (int k0 = 0; k0 < K; k0 += 64){
    #pragma unroll
    for (int i = 0; i < 4; i++){
      int c = tid + 256 * i;        // 1024 chunks of 8 bf16
      int row = c >> 3, koff = (c & 7) * 8;
      *(bf16x8*)&As[row * 72 + koff] = *(const bf16x8*)&Ad[(m0 + row) * K + k0 + koff];
      *(bf16x8*)&Bs[row * 72 + koff] = *(const bf16x8*)&Wd[(long)(n0 + row) * K + k0 + koff];
    }
    __syncthreads();
    #pragma unroll
    for (int kk = 0; kk < 64; kk += 32){
      bf16x8 af[4], bfr[4];
      #pragma unroll
      for (int mi = 0; mi < 4; mi++) af[mi]  = *(bf16x8*)&As[(wm + mi*16 + ln16) * 72 + kk + quad*8];
      #pragma unroll
      for (int nj = 0; nj < 4; nj++) bfr[nj] = *(bf16x8*)&Bs[(wn + nj*16 + ln16) * 72 + kk + quad*8];
      #pragma unroll
      for (int mi = 0; mi < 4; mi++)
        #pragma unroll
        for (int nj = 0; nj < 4; nj++)
          acc[mi][nj] = __builtin_amdgcn_mfma_f32_16x16x32_bf16(af[mi], bfr[nj], acc[mi][nj], 0, 0, 0);
    }
    __syncthreads();
  }
  // swizzled epilogue
  #pragma unroll
  for (int mi = 0; mi < 4; mi++)
    #pragma unroll
    for (int nj = 0; nj < 4; nj++){
      int n = n0 + wn + nj*16 + ln16;       // 0..767 within dir
      int g = n >> 8, c = n & 255;
      int w = c >> 5, ii = (c >> 4) & 1;
      float bv = bf2f(bd[n]);
      #pragma unroll
      for (int r = 0; r < 4; r++){
        long m = m0 + wm + mi*16 + quad*4 + r;
        int tl = (int)(m >> 8);
        int bgx = ((int)m & 255) >> 4;      // m&15 == quad*4+r
        long rec = (((long)tl*16 + bgx)*8 + w)*64 + quad*16 + ln16;
        unsigned short val = f2bf(acc[mi][nj][r] + bv);
        if (g < 2) rzd[rec*16 + ii*8 + g*4 + r] = val;
        else       nd [rec*8  + ii*4 + r]       = val;
      }
    }
}

// ---------------- GRU recurrence over one 64-step chunk, both dirs ----------------
// grid = 32 blocks (dir = blk>>4, batch group of 16 = blk&15), 512 threads (8 waves).
// ROUND-8 POST-MORTEM: hand-rolled lgkmcnt barrier + sched_barrier(0) REGRESSED
// (196->278us) -- order-pinning defeats the compiler's own ds_read pipelining.
// Reverted to plain __syncthreads (round-6 structure, proven 194us).
// ROUND-7 LESSON: the 7.3K cyc/step floor is a sum of per-CU THROUGHPUT terms;
// the largest is the LDS port: 192-256 ds_read_b128/step/CU x ~12cyc ~= 2.3-3.1K.
// Half of those reads are the n-gate weight re-reads from LDS.
// THIS VERSION: ALL THREE gates' weights laundered into registers (192 regs) --
// round-4/5's layout, which failed only because the allocator sank the loads;
// round 6 PROVED asm-laundering prevents that. LDS traffic/step drops to 64
// ds_read_b128 (h only) + h writes. LDS = 17KB h-dbuf only.
// xp loads for step ss issued at TOP of step ss, consumed ~2K cyc later in the
// epilogue: latency hides under the MFMA loop, no double-buffer regs, and the
// loads retire before their own step's barrier drain.
// Budget at waves_per_eu(2,2) (256 regs): 192 weights + 24 acc + 12 xp + ~26 misc.
__global__ __attribute__((amdgpu_flat_work_group_size(512, 512), amdgpu_waves_per_eu(2, 2)))
void k_gru_chunk(const unsigned short* __restrict__ xprz,
                 const unsigned short* __restrict__ xpn,
                 const unsigned short* __restrict__ whh,
                 const unsigned short* __restrict__ bhh,
                 float* __restrict__ hstate,  // [2][256][256]
                 unsigned short* __restrict__ outf,
                 unsigned short* __restrict__ outb,
                 int out_full, int t0f, int t0b){
  extern __shared__ __align__(16) unsigned short hbuf[];   // [2][HBUF_SH]

  int tid = threadIdx.x;
  int dir = blockIdx.x >> 4;
  int bg  = blockIdx.x & 15;
  int b0  = bg * 16;
  int wave = tid >> 6, lane = tid & 63;
  int ln16 = lane & 15, quad = lane >> 4;
  unsigned short* outp = dir ? outb : outf;
  int t0 = dir ? t0b : t0f;

  const unsigned short* rzbase = xprz + (long)dir * RZ_DIR + ((long)(bg*8 + wave)*64 + lane) * 16;
  const unsigned short* nbase  = xpn  + (long)dir * N_DIR  + ((long)(bg*8 + wave)*64 + lane) * 8;

  // ALL THREE gates' weight fragments register-resident (192 regs), laundered so
  // the allocator cannot sink the loads back into the step loop (round-6 proof).
  bf16x8 wr[2][8], wz[2][8], wn[2][8];
  #pragma unroll
  for (int i = 0; i < 2; i++){
    int c = (wave*2 + i)*16 + ln16;
    const unsigned short* Wb = whh + ((long)(dir*768 + c)) * 256 + quad*8;
    #pragma unroll
    for (int kt = 0; kt < 8; kt++){
      wr[i][kt] = *(const bf16x8*)(Wb + kt*32);
      wz[i][kt] = *(const bf16x8*)(Wb + 256*256 + kt*32);
      wn[i][kt] = *(const bf16x8*)(Wb + 512*256 + kt*32);
      asm volatile("" : "+v"(wr[i][kt]), "+v"(wz[i][kt]), "+v"(wn[i][kt]));
    }
  }

  // carried state -> regs + LDS buffer 0
  float h_old[2][4];
  #pragma unroll
  for (int i = 0; i < 2; i++){
    int c = (wave*2 + i)*16 + ln16;
    #pragma unroll
    for (int r = 0; r < 4; r++){
      int b = quad*4 + r;
      float hv = hstate[((long)dir*256 + b0 + b)*256 + c];
      h_old[i][r] = hv;
      hbuf[b * 264 + c] = f2bf(hv);
    }
  }
  float bh_n[2];
  #pragma unroll
  for (int i = 0; i < 2; i++){
    int c = (wave*2 + i)*16 + ln16;
    bh_n[i] = bf2f(bhh[dir*768 + 512 + c]);
  }

  int tl = dir ? (CT-1) : 0;
  __syncthreads();

  int p = 0;
  for (int ss = 0; ss < CT; ss++){
    // xp loads for THIS step, issued at step top: consumed in the epilogue
    // after ~24 MFMA + 8 ds_read -- L2/L3/HBM latency hides under compute,
    // and the loads retire before this step's own barrier drain.
    bf16x8 c_rz0 = *(const bf16x8*)(rzbase + (long)tl*RZ_TL);
    bf16x8 c_rz1 = *(const bf16x8*)(rzbase + (long)tl*RZ_TL + 8);
    bf16x8 c_n   = *(const bf16x8*)(nbase  + (long)tl*N_TL);

    unsigned short* hb_cur = hbuf + p*HBUF_SH;
    unsigned short* hb_nxt = hbuf + (1-p)*HBUF_SH;

    f32x4 ar[2], az[2], an[2];
    #pragma unroll
    for (int i = 0; i < 2; i++){
      ar[i] = (f32x4){0.f,0.f,0.f,0.f};
      az[i] = (f32x4){0.f,0.f,0.f,0.f};
      an[i] = (f32x4){0.f,0.f,0.f,0.f};
    }

    #pragma unroll
    for (int kt = 0; kt < 8; kt++){
      bf16x8 afb = *(bf16x8*)&hb_cur[ln16*264 + kt*32 + quad*8];
      ar[0] = __builtin_amdgcn_mfma_f32_16x16x32_bf16(afb, wr[0][kt], ar[0], 0, 0, 0);
      az[0] = __builtin_amdgcn_mfma_f32_16x16x32_bf16(afb, wz[0][kt], az[0], 0, 0, 0);
      an[0] = __builtin_amdgcn_mfma_f32_16x16x32_bf16(afb, wn[0][kt], an[0], 0, 0, 0);
      ar[1] = __builtin_amdgcn_mfma_f32_16x16x32_bf16(afb, wr[1][kt], ar[1], 0, 0, 0);
      az[1] = __builtin_amdgcn_mfma_f32_16x16x32_bf16(afb, wz[1][kt], az[1], 0, 0, 0);
      an[1] = __builtin_amdgcn_mfma_f32_16x16x32_bf16(afb, wn[1][kt], an[1], 0, 0, 0);
    }

    #pragma unroll
    for (int i = 0; i < 2; i++){
      int c = (wave*2 + i)*16 + ln16;
      #pragma unroll
      for (int r = 0; r < 4; r++){
        float xr = bf2f((unsigned short)(i ? c_rz1[r]   : c_rz0[r]));
        float xz = bf2f((unsigned short)(i ? c_rz1[4+r] : c_rz0[4+r]));
        float xn = bf2f((unsigned short)c_n[i*4 + r]);
        float rg = sigm(xr + ar[i][r]);                    // b_hh_r already in xr
        float zg = sigm(xz + az[i][r]);                    // b_hh_z already in xz
        float ng = tanh_f(xn + rg * (an[i][r] + bh_n[i]));
        float hnew = (1.f - zg) * ng + zg * h_old[i][r];
        h_old[i][r] = hnew;
        unsigned short hb = f2bf(hnew);
        int b = b0 + quad*4 + r;
        hb_nxt[(quad*4 + r) * 264 + c] = hb;
        long oidx = out_full ? (((long)(t0 + tl) * 256 + b) * 512 + dir*256 + c)
                             : (((long)tl * 256 + b) * 256 + c);
        outp[oidx] = hb;
      }
    }
    __syncthreads();
    p ^= 1;
    tl = dir ? tl-1 : tl+1;   // out-of-range after the last step, never used
  }

  #pragma unroll
  for (int i = 0; i < 2; i++){
    int c = (wave*2 + i)*16 + ln16;
    #pragma unroll
    for (int r = 0; r < 4; r++)
      hstate[((long)dir*256 + b0 + quad*4 + r)*256 + c] = h_old[i][r];
  }
}

// ------- FC1 per-chunk split-K, both dirs (grid.y): fc1acc += h2[dir] @ W1_dir-slice -------
__global__ __launch_bounds__(256) void k_fc1_chunk(const unsigned short* __restrict__ h2,
                                                   const void* __restrict__ W1,
                                                   const unsigned* __restrict__ w1f,
                                                   int t0f, int t0b,
                                                   float* __restrict__ fc1acc){
  int dir = blockIdx.y;
  const unsigned short* h2d = h2 + (long)dir * CROWS * 256;
  int t0 = dir ? t0b : t0f;
  int dircol = dir * 256;
  int mb = blockIdx.x & 3, kb = blockIdx.x >> 2;
  int wave = threadIdx.x >> 6, lane = threadIdx.x & 63;
  int ln16 = lane & 15, quad = lane >> 4;
  int w1fp32 = (int)*w1f;
  f32x4 acc[8];
  #pragma unroll
  for (int nt = 0; nt < 8; nt++) acc[nt] = (f32x4){0.f,0.f,0.f,0.f};

  for (int tt = 0; tt < 4; tt++){
    int tl = kb*4 + tt;
    const unsigned short* A = h2d + ((long)tl * 256 + mb*64 + wave*16) * 256;
    long bbase = (long)(t0 + tl) * 512 + dircol;
    #pragma unroll
    for (int kt = 0; kt < 8; kt++){
      bf16x8 af = *(const bf16x8*)(A + (long)ln16*256 + kt*32 + quad*8);
      #pragma unroll
      for (int nt = 0; nt < 8; nt++){
        long off = bbase + (long)(nt*16 + ln16)*262144 + kt*32 + quad*8;
        bf16x8 bfr;
        if (w1fp32){
          const float* pp = (const float*)W1 + off;
          #pragma unroll
          for (int j = 0; j < 8; j++) bfr[j] = (short)f2bf(pp[j]);
        } else {
          bfr = *(const bf16x8*)((const unsigned short*)W1 + off);
        }
        acc[nt] = __builtin_amdgcn_mfma_f32_16x16x32_bf16(af, bfr, acc[nt], 0, 0, 0);
      }
    }
  }
  #pragma unroll
  for (int nt = 0; nt < 8; nt++)
    #pragma unroll
    for (int r = 0; r < 4; r++){
      int m = mb*64 + wave*16 + quad*4 + r;
      int n = nt*16 + ln16;
      atomicAdd(&fc1acc[m*128 + n], acc[nt][r]);
    }
}

// ------- final: leaky_relu(fc1acc + b1) @ W2 + b2 -> sigmoid -------
__global__ __launch_bounds__(256) void k_fc2(const float* __restrict__ fc1acc,
                                             const unsigned short* __restrict__ b1,
                                             const unsigned short* __restrict__ W2,
                                             const unsigned short* __restrict__ b2,
                                             const unsigned* __restrict__ flags,
                                             void* __restrict__ out){
  int b = threadIdx.x;
  float s = bf2f(b2[0]);
  for (int j = 0; j < 128; j++){
    float v = fc1acc[b*128 + j] + bf2f(b1[j]);
    v = v > 0.f ? v : 0.01f * v;
    s += v * bf2f(W2[j]);
  }
  float r = sigm(s);
  if (flags[1]) ((float*)out)[b] = r;          // fp32 world -> fp32 output
  else          ((unsigned short*)out)[b] = f2bf(r);
}

extern "C" void kernel_launch(void* const* d_in, const int* in_sizes, int n_in,
                              void* d_out, int out_size, void* d_ws, size_t ws_size,
                              hipStream_t stream) {
  const void* inp  = d_in[0];
  const void* emb  = d_in[1];
  const void* wih0 = d_in[2];
  const void* whh0 = d_in[3];
  const void* bih0 = d_in[4];
  const void* bhh0 = d_in[5];
  const void* wih1 = d_in[6];
  const void* whh1 = d_in[7];
  const void* bih1 = d_in[8];
  const void* bhh1 = d_in[9];
  const void* W1   = d_in[10];
  const void* b1   = d_in[11];
  const void* W2   = d_in[12];
  const void* b2   = d_in[13];
  unsigned short* out = (unsigned short*)d_out;

  const int expect[14] = {131072, 8320, 196608, 393216, 1536, 1536,
                          786432, 393216, 1536, 1536, 33554432, 128, 128, 1};
  for (int i = 0; i < 14 && i < n_in; i++){
    if (in_sizes[i] != expect[i]){
      k_sentinel<<<1, 256, 0, stream>>>(out, 4.0f * (600.0f + i));
      return;
    }
  }

  // dynamic LDS attr (idempotent host-side attr, not a stream op; 17 KB now)
  static int smem_set = 0;
  if (!smem_set){
    hipFuncSetAttribute((const void*)k_gru_chunk,
                        hipFuncAttributeMaxDynamicSharedMemorySize, GRU_SMEM);
    smem_set = 1;
  }

  // workspace layout (bytes)
  const size_t OFF_X    = 0;                       // x    [131072*128] bf16
  const size_t OFF_H1   = 33554432ul;              // h1   [131072*512] bf16
  const size_t OFF_XPRZ = 167772160ul;             // xprz [2][RZ_DIR] bf16 (33.6 MB)
  const size_t OFF_XPN  = 201326592ul;             // xpn  [2][N_DIR]  bf16 (16.8 MB)
  const size_t OFF_H2   = 218103808ul;             // h2   [2][16384*256] bf16 (16.8 MB)
  const size_t OFF_ST   = 234881024ul;             // hstate [2*256*256] f32
  const size_t OFF_FC   = 235405312ul;             // fc1acc [256*128] f32
  const size_t OFF_FLAG = 235536384ul;             // 16 flag words
  const size_t OFF_P    = 235536448ul;             // converted bf16 params (~3.6 MB)
  unsigned short* P;
  const size_t PO_EMB  = 0;        // 8320
  const size_t PO_WIH0 = 8320;     // 196608
  const size_t PO_WHH0 = 204928;   // 393216
  const size_t PO_BIH0 = 598144;   // 1536
  const size_t PO_BHH0 = 599680;   // 1536
  const size_t PO_WIH1 = 601216;   // 786432
  const size_t PO_WHH1 = 1387648;  // 393216
  const size_t PO_BIH1 = 1780864;  // 1536
  const size_t PO_BHH1 = 1782400;  // 1536
  const size_t PO_B1   = 1783936;  // 128
  const size_t PO_W2   = 1784064;  // 128
  const size_t PO_B2   = 1784192;  // 1 (+pad)
  const size_t PO_CB0  = 1784200;  // combined bias layer0 [2*768]
  const size_t PO_CB1  = 1785736;  // combined bias layer1 [2*768]
  const size_t NEED    = OFF_P + 2*(1785736ul + 1536ul);

  if (ws_size < NEED) {
    k_sentinel<<<1, 256, 0, stream>>>(out, (float)(ws_size >> 20));
    return;
  }

  char* ws = (char*)d_ws;
  unsigned short* x    = (unsigned short*)(ws + OFF_X);
  unsigned short* h1   = (unsigned short*)(ws + OFF_H1);
  unsigned short* xprz = (unsigned short*)(ws + OFF_XPRZ);
  unsigned short* xpn  = (unsigned short*)(ws + OFF_XPN);
  unsigned short* h2   = (unsigned short*)(ws + OFF_H2);
  unsigned short* h2b  = h2 + (long)CROWS*256;
  float*          hst  = (float*)(ws + OFF_ST);
  float*          fc1a = (float*)(ws + OFF_FC);
  unsigned*       flg  = (unsigned*)(ws + OFF_FLAG);
  P = (unsigned short*)(ws + OFF_P);

  hipMemsetAsync(flg, 0, 64, stream);

  // ---- dtype probes ----
  k_probe_f<<<1,256,0,stream>>>((const unsigned short*)emb,  8320,     flg+1);
  k_probe_f<<<1,256,0,stream>>>((const unsigned short*)wih0, 196608,   flg+2);
  k_probe_f<<<1,256,0,stream>>>((const unsigned short*)whh0, 393216,   flg+3);
  k_probe_f<<<1,256,0,stream>>>((const unsigned short*)bih0, 1536,     flg+4);
  k_probe_f<<<1,256,0,stream>>>((const unsigned short*)bhh0, 1536,     flg+5);
  k_probe_f<<<1,256,0,stream>>>((const unsigned short*)wih1, 786432,   flg+6);
  k_probe_f<<<1,256,0,stream>>>((const unsigned short*)whh1, 393216,   flg+7);
  k_probe_f<<<1,256,0,stream>>>((const unsigned short*)bih1, 1536,     flg+8);
  k_probe_f<<<1,256,0,stream>>>((const unsigned short*)bhh1, 1536,     flg+9);
  k_probe_f<<<1,256,0,stream>>>((const unsigned short*)b1,   128,      flg+10);
  k_probe_f<<<1,256,0,stream>>>((const unsigned short*)W2,   128,      flg+11);
  k_probe_f<<<1,256,0,stream>>>((const unsigned short*)b2,   1,        flg+12);
  k_probe_f<<<1,256,0,stream>>>((const unsigned short*)W1,   33554432, flg+13);
  k_probe_i<<<1,256,0,stream>>>((const int*)inp, 131072, flg+14);

  // ---- convert params to bf16 ----
  k_convert<<<64,256,0,stream>>>(emb,  8320,   flg+1,  P+PO_EMB);
  k_convert<<<64,256,0,stream>>>(wih0, 196608, flg+2,  P+PO_WIH0);
  k_convert<<<64,256,0,stream>>>(whh0, 393216, flg+3,  P+PO_WHH0);
  k_convert<<<8, 256,0,stream>>>(bih0, 1536,   flg+4,  P+PO_BIH0);
  k_convert<<<8, 256,0,stream>>>(bhh0, 1536,   flg+5,  P+PO_BHH0);
  k_convert<<<64,256,0,stream>>>(wih1, 786432, flg+6,  P+PO_WIH1);
  k_convert<<<64,256,0,stream>>>(whh1, 393216, flg+7,  P+PO_WHH1);
  k_convert<<<8, 256,0,stream>>>(bih1, 1536,   flg+8,  P+PO_BIH1);
  k_convert<<<8, 256,0,stream>>>(bhh1, 1536,   flg+9,  P+PO_BHH1);
  k_convert<<<1, 256,0,stream>>>(b1,   128,    flg+10, P+PO_B1);
  k_convert<<<1, 256,0,stream>>>(W2,   128,    flg+11, P+PO_W2);
  k_convert<<<1, 256,0,stream>>>(b2,   1,      flg+12, P+PO_B2);

  // ---- combined biases (b_ih + b_hh for r,z gates) ----
  k_prep_bias<<<6,256,0,stream>>>(P+PO_BIH0, P+PO_BHH0, P+PO_CB0);
  k_prep_bias<<<6,256,0,stream>>>(P+PO_BIH1, P+PO_BHH1, P+PO_CB1);

  k_embed<<<MM*16/256, 256, 0, stream>>>(P+PO_EMB, inp, flg+14, x);

  // ---- layer 0 ----
  hipMemsetAsync(hst, 0, 2*256*256*sizeof(float), stream);
  for (int c = 0; c < NCH; c++){
    int t0f = c * CT, t0b = (NCH - 1 - c) * CT;
    k_gemm_chunk<128><<<dim3(CROWS/128, 6, 2), 256, 0, stream>>>(x, P+PO_WIH0, P+PO_CB0, xprz, xpn, t0f, t0b);
    k_gru_chunk<<<32, 512, GRU_SMEM, stream>>>(xprz, xpn, P+PO_WHH0, P+PO_BHH0, hst, h1, h1, 1, t0f, t0b);
  }

  // ---- layer 1 (+ fused FC1 accumulation) ----
  hipMemsetAsync(hst, 0, 2*256*256*sizeof(float), stream);
  hipMemsetAsync(fc1a, 0, 256*128*sizeof(float), stream);
  for (int c = 0; c < NCH; c++){
    int t0f = c * CT, t0b = (NCH - 1 - c) * CT;
    k_gemm_chunk<512><<<dim3(CROWS/128, 6, 2), 256, 0, stream>>>(h1, P+PO_WIH1, P+PO_CB1, xprz, xpn, t0f, t0b);
    k_gru_chunk<<<32, 512, GRU_SMEM, stream>>>(xprz, xpn, P+PO_WHH1, P+PO_BHH1, hst, h2, h2b, 0, t0f, t0b);
    k_fc1_chunk<<<dim3(64, 2), 256, 0, stream>>>(h2, W1, flg+13, t0f, t0b, fc1a);
  }

  k_fc2<<<1, 256, 0, stream>>>(fc1a, P+PO_B1, P+PO_W2, P+PO_B2, flg, d_out);
}

// Round 10
// 5606.521 us; speedup vs baseline: 1.2190x; 1.2185x over previous
//
#include <hip/hip_runtime.h>
#include <hip/hip_bf16.h>
#include <stdint.h>

// Problem dims
#define BB 256
#define TT 512
#define EE 128
#define HH 256
#define MM (TT*BB)       // 131072 rows total
#define CT 64            // timesteps per chunk
#define NCH (TT/CT)      // 8 chunks
#define CROWS (CT*BB)    // 16384 rows per chunk
// swizzled xp sizes (shorts)
#define RZ_DIR 8388608   // 64*16*8*64*16
#define RZ_TL  131072    // 16*8*64*16
#define N_DIR  4194304   // 64*16*8*64*8
#define N_TL   65536
// GRU dynamic LDS: swizzled n-gate weights [16g][8kt][64lane][8] + h dbuf [2][16*264]
#define WN_SH   65536                 // shorts (128 KB)
#define HBUF_SH (16*264)              // shorts per buffer
#define GRU_SMEM ((WN_SH + 2*HBUF_SH) * 2)   // bytes = 147968 (<= 160K)

typedef __attribute__((ext_vector_type(8))) short bf16x8;
typedef __attribute__((ext_vector_type(4))) float f32x4;

__device__ __forceinline__ float bf2f(unsigned short u){
  union { unsigned int i; float f; } v; v.i = ((unsigned int)u) << 16; return v.f;
}
__device__ __forceinline__ unsigned short f2bf(float f){
  union { float f; unsigned int i; } v; v.f = f;
  unsigned int u = v.i;
  unsigned int r = (u + 0x7FFFu + ((u >> 16) & 1u)) >> 16;
  return (unsigned short)r;
}
__device__ __forceinline__ float sigm(float x){ return 1.f / (1.f + __expf(-x)); }
__device__ __forceinline__ float tanh_f(float x){
  float e2 = __expf(2.f * x);
  return 1.f - 2.f / (e2 + 1.f);
}

// -------- sentinel --------
__global__ void k_sentinel(unsigned short* out, float v){ out[threadIdx.x] = f2bf(v); }

// -------- dtype probe: is this float tensor fp32 (vs bf16)? --------
__global__ void k_probe_f(const unsigned short* __restrict__ buf, int n,
                          unsigned* __restrict__ flagw){
  __shared__ int cnt;
  if (threadIdx.x == 0) cnt = 0;
  __syncthreads();
  int scanw = n < 4096 ? n : 4096;
  int bad = 0;
  for (int i = threadIdx.x; i < scanw; i += 256){
    unsigned short u = buf[i];
    unsigned e = (u >> 7) & 0xFF;
    if (u != 0 && (e < 0x60 || e == 0xFF)) bad++;
  }
  atomicAdd(&cnt, bad);
  __syncthreads();
  if (threadIdx.x == 0) *flagw = (cnt * 8 > scanw) ? 1u : 0u;
}

// -------- int width probe: int64 iff odd int32 words are (almost) all zero --------
__global__ void k_probe_i(const int* __restrict__ buf, int n, unsigned* __restrict__ flagw){
  __shared__ int cnt;
  if (threadIdx.x == 0) cnt = 0;
  __syncthreads();
  int scan = n < 1024 ? n : 1024;
  int nz = 0;
  for (int i = threadIdx.x; i < scan; i += 256)
    if ((i & 1) && buf[i] != 0) nz++;
  atomicAdd(&cnt, nz);
  __syncthreads();
  if (threadIdx.x == 0) *flagw = (cnt < 10) ? 1u : 0u;
}

// -------- convert a float tensor (fp32 or bf16 per flag) to bf16 dst --------
__global__ __launch_bounds__(256) void k_convert(const void* __restrict__ src, int n,
                                                 const unsigned* __restrict__ flagw,
                                                 unsigned short* __restrict__ dst){
  int fp32 = (int)*flagw;
  int i0 = blockIdx.x * 256 + threadIdx.x;
  int stride = gridDim.x * 256;
  if (fp32){
    const float* s = (const float*)src;
    for (int i = i0; i < n; i += stride) dst[i] = f2bf(s[i]);
  } else {
    const unsigned short* s = (const unsigned short*)src;
    for (int i = i0; i < n; i += stride) dst[i] = s[i];
  }
}

// -------- combined bias: cb[dir][n] = b_ih[dir][n] + (n < 512 ? b_hh[dir][n] : 0) --------
// NOTE: 768 is NOT a power of two -- must use %, not & (round-1 bug).
__global__ __launch_bounds__(256) void k_prep_bias(const unsigned short* __restrict__ bih,
                                                   const unsigned short* __restrict__ bhh,
                                                   unsigned short* __restrict__ cb){
  int i = blockIdx.x * 256 + threadIdx.x;   // 0..1535 (2 dirs x 768)
  if (i >= 1536) return;
  int n = i % 768;
  float v = bf2f(bih[i]);
  if (n < 512) v += bf2f(bhh[i]);
  cb[i] = f2bf(v);
}

// ---------------- embed: x[t*B+b][e] = embc[inputs[b][t]][e] (bf16) ----------------
__global__ __launch_bounds__(256) void k_embed(const unsigned short* __restrict__ embc,
                                               const void* __restrict__ inputs,
                                               const unsigned* __restrict__ i64f,
                                               unsigned short* __restrict__ x){
  int c = blockIdx.x * 256 + threadIdx.x;  // 16B chunk id; total = MM*16
  int e8 = (c & 15) * 8;
  int tb = c >> 4;
  int t = tb >> 8;
  int b = tb & 255;
  long k = (long)b * TT + t;
  int idx = (*i64f) ? ((const int*)inputs)[k * 2] : ((const int*)inputs)[k];
  idx = idx < 0 ? 0 : (idx > 64 ? 64 : idx);
  *(bf16x8*)(x + (long)tb * EE + e8) = *(const bf16x8*)(embc + (long)idx * EE + e8);
}

// ------- chunk xp GEMM, both dirs (grid.z), epilogue writes GRU-swizzled xp -------
template<int K>
__global__ __launch_bounds__(256) void k_gemm_chunk(const unsigned short* __restrict__ A,
                                                    const unsigned short* __restrict__ W,
                                                    const unsigned short* __restrict__ bias,
                                                    unsigned short* __restrict__ xprz,
                                                    unsigned short* __restrict__ xpn,
                                                    int t0f, int t0b){
  __shared__ __align__(16) unsigned short As[128 * 72];
  __shared__ __align__(16) unsigned short Bs[128 * 72];
  int dir = blockIdx.z;
  const unsigned short* Ad = A + (long)(dir ? t0b : t0f) * 256 * K;
  const unsigned short* Wd = W + (long)dir * 768 * K;
  const unsigned short* bd = bias + dir * 768;
  unsigned short* rzd = xprz + (long)dir * RZ_DIR;
  unsigned short* nd  = xpn  + (long)dir * N_DIR;

  int tid = threadIdx.x;
  long m0 = (long)blockIdx.x * 128;
  int  n0 = blockIdx.y * 128;
  int wave = tid >> 6, lane = tid & 63;
  int wm = (wave & 1) * 64, wn = (wave >> 1) * 64;
  int ln16 = lane & 15, quad = lane >> 4;
  f32x4 acc[4][4];
  #pragma unroll
  for (int i = 0; i < 4; i++)
    #pragma unroll
    for (int j = 0; j < 4; j++) acc[i][j] = (f32x4){0.f,0.f,0.f,0.f};

  for (int k0 = 0; k0 < K; k0 += 64){
    #pragma unroll
    for (int i = 0; i < 4; i++){
      int c = tid + 256 * i;        // 1024 chunks of 8 bf16
      int row = c >> 3, koff = (c & 7) * 8;
      *(bf16x8*)&As[row * 72 + koff] = *(const bf16x8*)&Ad[(m0 + row) * K + k0 + koff];
      *(bf16x8*)&Bs[row * 72 + koff] = *(const bf16x8*)&Wd[(long)(n0 + row) * K + k0 + koff];
    }
    __syncthreads();
    #pragma unroll
    for (int kk = 0; kk < 64; kk += 32){
      bf16x8 af[4], bfr[4];
      #pragma unroll
      for (int mi = 0; mi < 4; mi++) af[mi]  = *(bf16x8*)&As[(wm + mi*16 + ln16) * 72 + kk + quad*8];
      #pragma unroll
      for (int nj = 0; nj < 4; nj++) bfr[nj] = *(bf16x8*)&Bs[(wn + nj*16 + ln16) * 72 + kk + quad*8];
      #pragma unroll
      for (int mi = 0; mi < 4; mi++)
        #pragma unroll
        for (int nj = 0; nj < 4; nj++)
          acc[mi][nj] = __builtin_amdgcn_mfma_f32_16x16x32_bf16(af[mi], bfr[nj], acc[mi][nj], 0, 0, 0);
    }
    __syncthreads();
  }
  // swizzled epilogue
  #pragma unroll
  for (int mi = 0; mi < 4; mi++)
    #pragma unroll
    for (int nj = 0; nj < 4; nj++){
      int n = n0 + wn + nj*16 + ln16;       // 0..767 within dir
      int g = n >> 8, c = n & 255;
      int w = c >> 5, ii = (c >> 4) & 1;
      float bv = bf2f(bd[n]);
      #pragma unroll
      for (int r = 0; r < 4; r++){
        long m = m0 + wm + mi*16 + quad*4 + r;
        int tl = (int)(m >> 8);
        int bgx = ((int)m & 255) >> 4;      // m&15 == quad*4+r
        long rec = (((long)tl*16 + bgx)*8 + w)*64 + quad*16 + ln16;
        unsigned short val = f2bf(acc[mi][nj][r] + bv);
        if (g < 2) rzd[rec*16 + ii*8 + g*4 + r] = val;
        else       nd [rec*8  + ii*4 + r]       = val;
      }
    }
}

// ---------------- GRU recurrence over one 64-step chunk, both dirs ----------------
// grid = 32 blocks (dir = blk>>4, batch group of 16 = blk&15), 512 threads (8 waves).
// ROUND-9 POST-MORTEM: 192 laundered weights -> allocator parked them in AGPRs
// with in-loop copies; 299us REGRESSION. Round-6 structure (194us) restored:
// wn in LDS fragment-major (conflict-free), 128 laundered r/z regs, 8 waves.
// ROUND-10 SINGLE-VARIABLE EXPERIMENT: the in-loop __syncthreads emits
// `s_waitcnt vmcnt(0) lgkmcnt(0)` before s_barrier -- draining the 8 scattered
// global stores + prefetch-load tails into every one of the 64 serial steps.
// Replace ONLY the in-loop barrier with `s_waitcnt lgkmcnt(0); s_barrier`
// (memory clobber, NO sched_barrier -- round-8's regression came from
// sched_barrier(0) order-pinning, not from the counted wait itself).
// Legality: the barrier protects only the LDS h double-buffer (lgkmcnt);
// global stores are never read in-kernel; xp loads feed only the issuing
// wave's own registers (compiler inserts consumer-side vmcnt waits at use).
__global__ __attribute__((amdgpu_flat_work_group_size(512, 512), amdgpu_waves_per_eu(2, 2)))
void k_gru_chunk(const unsigned short* __restrict__ xprz,
                 const unsigned short* __restrict__ xpn,
                 const unsigned short* __restrict__ whh,
                 const unsigned short* __restrict__ bhh,
                 float* __restrict__ hstate,  // [2][256][256]
                 unsigned short* __restrict__ outf,
                 unsigned short* __restrict__ outb,
                 int out_full, int t0f, int t0b){
  extern __shared__ __align__(16) unsigned short smem[];   // [WN_SH] + [2][HBUF_SH]
  unsigned short* wn_lds = smem;
  unsigned short* hbuf   = smem + WN_SH;

  int tid = threadIdx.x;
  int dir = blockIdx.x >> 4;
  int bg  = blockIdx.x & 15;
  int b0  = bg * 16;
  int wave = tid >> 6, lane = tid & 63;
  int ln16 = lane & 15, quad = lane >> 4;
  unsigned short* outp = dir ? outb : outf;
  int t0 = dir ? t0b : t0f;

  const unsigned short* rzbase = xprz + (long)dir * RZ_DIR + ((long)(bg*8 + wave)*64 + lane) * 16;
  const unsigned short* nbase  = xpn  + (long)dir * N_DIR  + ((long)(bg*8 + wave)*64 + lane) * 8;

  // stage n-gate weights into LDS, fragment-major swizzle: value W_n[c][j*8..+8]
  // (c = g*16+l16, j = kt*4+qd) lands at shorts[((g*8+kt)*64 + qd*16 + l16)*8].
  // Per-step read for (g,kt) is then wn_lds[((g*8+kt)*64 + lane)*8] -- 64 lanes
  // read 64 consecutive 16B slots = conflict-free ds_read_b128.
  for (int v = tid; v < 256*32; v += 512){
    int c = v >> 5, j = v & 31;
    int g = c >> 4, l16 = c & 15;
    int kt = j >> 2, qd = j & 3;
    *(bf16x8*)&wn_lds[(((g*8 + kt)*64) + qd*16 + l16) * 8] =
      *(const bf16x8*)&whh[((long)(dir*768 + 512 + c))*256 + j*8];
  }

  // r,z weight fragments register-resident (128 VGPR), laundered so the
  // scheduler cannot sink the loads back into the step loop.
  bf16x8 wr[2][8], wz[2][8];
  #pragma unroll
  for (int i = 0; i < 2; i++){
    int c = (wave*2 + i)*16 + ln16;
    const unsigned short* Wb = whh + ((long)(dir*768 + c)) * 256 + quad*8;
    #pragma unroll
    for (int kt = 0; kt < 8; kt++){
      wr[i][kt] = *(const bf16x8*)(Wb + kt*32);
      wz[i][kt] = *(const bf16x8*)(Wb + 256*256 + kt*32);
      asm volatile("" : "+v"(wr[i][kt]), "+v"(wz[i][kt]));
    }
  }

  // carried state -> regs + LDS buffer 0
  float h_old[2][4];
  #pragma unroll
  for (int i = 0; i < 2; i++){
    int c = (wave*2 + i)*16 + ln16;
    #pragma unroll
    for (int r = 0; r < 4; r++){
      int b = quad*4 + r;
      float hv = hstate[((long)dir*256 + b0 + b)*256 + c];
      h_old[i][r] = hv;
      hbuf[b * 264 + c] = f2bf(hv);
    }
  }
  float bh_n[2];
  #pragma unroll
  for (int i = 0; i < 2; i++){
    int c = (wave*2 + i)*16 + ln16;
    bh_n[i] = bf2f(bhh[dir*768 + 512 + c]);
  }

  int wnb0 = ((wave*2 + 0)*8)*64*8 + lane*8;   // shorts base, i=0 fragments
  int wnb1 = ((wave*2 + 1)*8)*64*8 + lane*8;   // i=1

  // prefetch first step's xp
  int tl = dir ? (CT-1) : 0;
  bf16x8 c_rz0 = *(const bf16x8*)(rzbase + (long)tl*RZ_TL);
  bf16x8 c_rz1 = *(const bf16x8*)(rzbase + (long)tl*RZ_TL + 8);
  bf16x8 c_n   = *(const bf16x8*)(nbase  + (long)tl*N_TL);
  __syncthreads();

  int p = 0;
  for (int ss = 0; ss < CT; ss++){
    int tln = (ss == CT-1) ? tl : (dir ? tl-1 : tl+1);

    unsigned short* hb_cur = hbuf + p*HBUF_SH;
    unsigned short* hb_nxt = hbuf + (1-p)*HBUF_SH;

    f32x4 ar[2], az[2], an[2];
    #pragma unroll
    for (int i = 0; i < 2; i++){
      ar[i] = (f32x4){0.f,0.f,0.f,0.f};
      az[i] = (f32x4){0.f,0.f,0.f,0.f};
      an[i] = (f32x4){0.f,0.f,0.f,0.f};
    }

    // 2-deep pipelined LDS reads: h A-fragment + conflict-free n-gate B-fragments
    bf16x8 afb[2], wnb[2][2];
    afb[0]    = *(bf16x8*)&hb_cur[ln16*264 + quad*8];
    wnb[0][0] = *(bf16x8*)&wn_lds[wnb0];
    wnb[0][1] = *(bf16x8*)&wn_lds[wnb1];
    #pragma unroll
    for (int kt = 0; kt < 8; kt++){
      int cur = kt & 1, nxt = cur ^ 1;
      if (kt < 7){
        afb[nxt]    = *(bf16x8*)&hb_cur[ln16*264 + (kt+1)*32 + quad*8];
        wnb[nxt][0] = *(bf16x8*)&wn_lds[wnb0 + (kt+1)*64*8];
        wnb[nxt][1] = *(bf16x8*)&wn_lds[wnb1 + (kt+1)*64*8];
      }
      ar[0] = __builtin_amdgcn_mfma_f32_16x16x32_bf16(afb[cur], wr[0][kt], ar[0], 0, 0, 0);
      az[0] = __builtin_amdgcn_mfma_f32_16x16x32_bf16(afb[cur], wz[0][kt], az[0], 0, 0, 0);
      an[0] = __builtin_amdgcn_mfma_f32_16x16x32_bf16(afb[cur], wnb[cur][0], an[0], 0, 0, 0);
      ar[1] = __builtin_amdgcn_mfma_f32_16x16x32_bf16(afb[cur], wr[1][kt], ar[1], 0, 0, 0);
      az[1] = __builtin_amdgcn_mfma_f32_16x16x32_bf16(afb[cur], wz[1][kt], az[1], 0, 0, 0);
      an[1] = __builtin_amdgcn_mfma_f32_16x16x32_bf16(afb[cur], wnb[cur][1], an[1], 0, 0, 0);
    }

    // prefetch next step's xp (post-MFMA: 12 VGPRs dead across peak-pressure region)
    bf16x8 n_rz0 = *(const bf16x8*)(rzbase + (long)tln*RZ_TL);
    bf16x8 n_rz1 = *(const bf16x8*)(rzbase + (long)tln*RZ_TL + 8);
    bf16x8 n_n   = *(const bf16x8*)(nbase  + (long)tln*N_TL);

    #pragma unroll
    for (int i = 0; i < 2; i++){
      int c = (wave*2 + i)*16 + ln16;
      #pragma unroll
      for (int r = 0; r < 4; r++){
        float xr = bf2f((unsigned short)(i ? c_rz1[r]   : c_rz0[r]));
        float xz = bf2f((unsigned short)(i ? c_rz1[4+r] : c_rz0[4+r]));
        float xn = bf2f((unsigned short)c_n[i*4 + r]);
        float rg = sigm(xr + ar[i][r]);                    // b_hh_r already in xr
        float zg = sigm(xz + az[i][r]);                    // b_hh_z already in xz
        float ng = tanh_f(xn + rg * (an[i][r] + bh_n[i]));
        float hnew = (1.f - zg) * ng + zg * h_old[i][r];
        h_old[i][r] = hnew;
        unsigned short hb = f2bf(hnew);
        int b = b0 + quad*4 + r;
        hb_nxt[(quad*4 + r) * 264 + c] = hb;
        long oidx = out_full ? (((long)(t0 + tl) * 256 + b) * 512 + dir*256 + c)
                             : (((long)tl * 256 + b) * 256 + c);
        outp[oidx] = hb;
      }
    }
    // LDS-only barrier: global stores and prefetch loads stay in flight.
    // (NO sched_barrier here -- that was round-8's regression.)
    asm volatile("s_waitcnt lgkmcnt(0)\n\ts_barrier" ::: "memory");
    p ^= 1;
    tl = tln;
    c_rz0 = n_rz0; c_rz1 = n_rz1; c_n = n_n;
  }

  #pragma unroll
  for (int i = 0; i < 2; i++){
    int c = (wave*2 + i)*16 + ln16;
    #pragma unroll
    for (int r = 0; r < 4; r++)
      hstate[((long)dir*256 + b0 + quad*4 + r)*256 + c] = h_old[i][r];
  }
}

// ------- FC1 per-chunk split-K, both dirs (grid.y): fc1acc += h2[dir] @ W1_dir-slice -------
__global__ __launch_bounds__(256) void k_fc1_chunk(const unsigned short* __restrict__ h2,
                                                   const void* __restrict__ W1,
                                                   const unsigned* __restrict__ w1f,
                                                   int t0f, int t0b,
                                                   float* __restrict__ fc1acc){
  int dir = blockIdx.y;
  const unsigned short* h2d = h2 + (long)dir * CROWS * 256;
  int t0 = dir ? t0b : t0f;
  int dircol = dir * 256;
  int mb = blockIdx.x & 3, kb = blockIdx.x >> 2;
  int wave = threadIdx.x >> 6, lane = threadIdx.x & 63;
  int ln16 = lane & 15, quad = lane >> 4;
  int w1fp32 = (int)*w1f;
  f32x4 acc[8];
  #pragma unroll
  for (int nt = 0; nt < 8; nt++) acc[nt] = (f32x4){0.f,0.f,0.f,0.f};

  for (int tt = 0; tt < 4; tt++){
    int tl = kb*4 + tt;
    const unsigned short* A = h2d + ((long)tl * 256 + mb*64 + wave*16) * 256;
    long bbase = (long)(t0 + tl) * 512 + dircol;
    #pragma unroll
    for (int kt = 0; kt < 8; kt++){
      bf16x8 af = *(const bf16x8*)(A + (long)ln16*256 + kt*32 + quad*8);
      #pragma unroll
      for (int nt = 0; nt < 8; nt++){
        long off = bbase + (long)(nt*16 + ln16)*262144 + kt*32 + quad*8;
        bf16x8 bfr;
        if (w1fp32){
          const float* pp = (const float*)W1 + off;
          #pragma unroll
          for (int j = 0; j < 8; j++) bfr[j] = (short)f2bf(pp[j]);
        } else {
          bfr = *(const bf16x8*)((const unsigned short*)W1 + off);
        }
        acc[nt] = __builtin_amdgcn_mfma_f32_16x16x32_bf16(af, bfr, acc[nt], 0, 0, 0);
      }
    }
  }
  #pragma unroll
  for (int nt = 0; nt < 8; nt++)
    #pragma unroll
    for (int r = 0; r < 4; r++){
      int m = mb*64 + wave*16 + quad*4 + r;
      int n = nt*16 + ln16;
      atomicAdd(&fc1acc[m*128 + n], acc[nt][r]);
    }
}

// ------- final: leaky_relu(fc1acc + b1) @ W2 + b2 -> sigmoid -------
__global__ __launch_bounds__(256) void k_fc2(const float* __restrict__ fc1acc,
                                             const unsigned short* __restrict__ b1,
                                             const unsigned short* __restrict__ W2,
                                             const unsigned short* __restrict__ b2,
                                             const unsigned* __restrict__ flags,
                                             void* __restrict__ out){
  int b = threadIdx.x;
  float s = bf2f(b2[0]);
  for (int j = 0; j < 128; j++){
    float v = fc1acc[b*128 + j] + bf2f(b1[j]);
    v = v > 0.f ? v : 0.01f * v;
    s += v * bf2f(W2[j]);
  }
  float r = sigm(s);
  if (flags[1]) ((float*)out)[b] = r;          // fp32 world -> fp32 output
  else          ((unsigned short*)out)[b] = f2bf(r);
}

extern "C" void kernel_launch(void* const* d_in, const int* in_sizes, int n_in,
                              void* d_out, int out_size, void* d_ws, size_t ws_size,
                              hipStream_t stream) {
  const void* inp  = d_in[0];
  const void* emb  = d_in[1];
  const void* wih0 = d_in[2];
  const void* whh0 = d_in[3];
  const void* bih0 = d_in[4];
  const void* bhh0 = d_in[5];
  const void* wih1 = d_in[6];
  const void* whh1 = d_in[7];
  const void* bih1 = d_in[8];
  const void* bhh1 = d_in[9];
  const void* W1   = d_in[10];
  const void* b1   = d_in[11];
  const void* W2   = d_in[12];
  const void* b2   = d_in[13];
  unsigned short* out = (unsigned short*)d_out;

  const int expect[14] = {131072, 8320, 196608, 393216, 1536, 1536,
                          786432, 393216, 1536, 1536, 33554432, 128, 128, 1};
  for (int i = 0; i < 14 && i < n_in; i++){
    if (in_sizes[i] != expect[i]){
      k_sentinel<<<1, 256, 0, stream>>>(out, 4.0f * (600.0f + i));
      return;
    }
  }

  // dynamic LDS attr (idempotent host-side attr, not a stream op; 145 KB)
  static int smem_set = 0;
  if (!smem_set){
    hipFuncSetAttribute((const void*)k_gru_chunk,
                        hipFuncAttributeMaxDynamicSharedMemorySize, GRU_SMEM);
    smem_set = 1;
  }

  // workspace layout (bytes)
  const size_t OFF_X    = 0;                       // x    [131072*128] bf16
  const size_t OFF_H1   = 33554432ul;              // h1   [131072*512] bf16
  const size_t OFF_XPRZ = 167772160ul;             // xprz [2][RZ_DIR] bf16 (33.6 MB)
  const size_t OFF_XPN  = 201326592ul;             // xpn  [2][N_DIR]  bf16 (16.8 MB)
  const size_t OFF_H2   = 218103808ul;             // h2   [2][16384*256] bf16 (16.8 MB)
  const size_t OFF_ST   = 234881024ul;             // hstate [2*256*256] f32
  const size_t OFF_FC   = 235405312ul;             // fc1acc [256*128] f32
  const size_t OFF_FLAG = 235536384ul;             // 16 flag words
  const size_t OFF_P    = 235536448ul;             // converted bf16 params (~3.6 MB)
  unsigned short* P;
  const size_t PO_EMB  = 0;        // 8320
  const size_t PO_WIH0 = 8320;     // 196608
  const size_t PO_WHH0 = 204928;   // 393216
  const size_t PO_BIH0 = 598144;   // 1536
  const size_t PO_BHH0 = 599680;   // 1536
  const size_t PO_WIH1 = 601216;   // 786432
  const size_t PO_WHH1 = 1387648;  // 393216
  const size_t PO_BIH1 = 1780864;  // 1536
  const size_t PO_BHH1 = 1782400;  // 1536
  const size_t PO_B1   = 1783936;  // 128
  const size_t PO_W2   = 1784064;  // 128
  const size_t PO_B2   = 1784192;  // 1 (+pad)
  const size_t PO_CB0  = 1784200;  // combined bias layer0 [2*768]
  const size_t PO_CB1  = 1785736;  // combined bias layer1 [2*768]
  const size_t NEED    = OFF_P + 2*(1785736ul + 1536ul);

  if (ws_size < NEED) {
    k_sentinel<<<1, 256, 0, stream>>>(out, (float)(ws_size >> 20));
    return;
  }

  char* ws = (char*)d_ws;
  unsigned short* x    = (unsigned short*)(ws + OFF_X);
  unsigned short* h1   = (unsigned short*)(ws + OFF_H1);
  unsigned short* xprz = (unsigned short*)(ws + OFF_XPRZ);
  unsigned short* xpn  = (unsigned short*)(ws + OFF_XPN);
  unsigned short* h2   = (unsigned short*)(ws + OFF_H2);
  unsigned short* h2b  = h2 + (long)CROWS*256;
  float*          hst  = (float*)(ws + OFF_ST);
  float*          fc1a = (float*)(ws + OFF_FC);
  unsigned*       flg  = (unsigned*)(ws + OFF_FLAG);
  P = (unsigned short*)(ws + OFF_P);

  hipMemsetAsync(flg, 0, 64, stream);

  // ---- dtype probes ----
  k_probe_f<<<1,256,0,stream>>>((const unsigned short*)emb,  8320,     flg+1);
  k_probe_f<<<1,256,0,stream>>>((const unsigned short*)wih0, 196608,   flg+2);
  k_probe_f<<<1,256,0,stream>>>((const unsigned short*)whh0, 393216,   flg+3);
  k_probe_f<<<1,256,0,stream>>>((const unsigned short*)bih0, 1536,     flg+4);
  k_probe_f<<<1,256,0,stream>>>((const unsigned short*)bhh0, 1536,     flg+5);
  k_probe_f<<<1,256,0,stream>>>((const unsigned short*)wih1, 786432,   flg+6);
  k_probe_f<<<1,256,0,stream>>>((const unsigned short*)whh1, 393216,   flg+7);
  k_probe_f<<<1,256,0,stream>>>((const unsigned short*)bih1, 1536,     flg+8);
  k_probe_f<<<1,256,0,stream>>>((const unsigned short*)bhh1, 1536,     flg+9);
  k_probe_f<<<1,256,0,stream>>>((const unsigned short*)b1,   128,      flg+10);
  k_probe_f<<<1,256,0,stream>>>((const unsigned short*)W2,   128,      flg+11);
  k_probe_f<<<1,256,0,stream>>>((const unsigned short*)b2,   1,        flg+12);
  k_probe_f<<<1,256,0,stream>>>((const unsigned short*)W1,   33554432, flg+13);
  k_probe_i<<<1,256,0,stream>>>((const int*)inp, 131072, flg+14);

  // ---- convert params to bf16 ----
  k_convert<<<64,256,0,stream>>>(emb,  8320,   flg+1,  P+PO_EMB);
  k_convert<<<64,256,0,stream>>>(wih0, 196608, flg+2,  P+PO_WIH0);
  k_convert<<<64,256,0,stream>>>(whh0, 393216, flg+3,  P+PO_WHH0);
  k_convert<<<8, 256,0,stream>>>(bih0, 1536,   flg+4,  P+PO_BIH0);
  k_convert<<<8, 256,0,stream>>>(bhh0, 1536,   flg+5,  P+PO_BHH0);
  k_convert<<<64,256,0,stream>>>(wih1, 786432, flg+6,  P+PO_WIH1);
  k_convert<<<64,256,0,stream>>>(whh1, 393216, flg+7,  P+PO_WHH1);
  k_convert<<<8, 256,0,stream>>>(bih1, 1536,   flg+8,  P+PO_BIH1);
  k_convert<<<8, 256,0,stream>>>(bhh1, 1536,   flg+9,  P+PO_BHH1);
  k_convert<<<1, 256,0,stream>>>(b1,   128,    flg+10, P+PO_B1);
  k_convert<<<1, 256,0,stream>>>(W2,   128,    flg+11, P+PO_W2);
  k_convert<<<1, 256,0,stream>>>(b2,   1,      flg+12, P+PO_B2);

  // ---- combined biases (b_ih + b_hh for r,z gates) ----
  k_prep_bias<<<6,256,0,stream>>>(P+PO_BIH0, P+PO_BHH0, P+PO_CB0);
  k_prep_bias<<<6,256,0,stream>>>(P+PO_BIH1, P+PO_BHH1, P+PO_CB1);

  k_embed<<<MM*16/256, 256, 0, stream>>>(P+PO_EMB, inp, flg+14, x);

  // ---- layer 0 ----
  hipMemsetAsync(hst, 0, 2*256*256*sizeof(float), stream);
  for (int c = 0; c < NCH; c++){
    int t0f = c * CT, t0b = (NCH - 1 - c) * CT;
    k_gemm_chunk<128><<<dim3(CROWS/128, 6, 2), 256, 0, stream>>>(x, P+PO_WIH0, P+PO_CB0, xprz, xpn, t0f, t0b);
    k_gru_chunk<<<32, 512, GRU_SMEM, stream>>>(xprz, xpn, P+PO_WHH0, P+PO_BHH0, hst, h1, h1, 1, t0f, t0b);
  }

  // ---- layer 1 (+ fused FC1 accumulation) ----
  hipMemsetAsync(hst, 0, 2*256*256*sizeof(float), stream);
  hipMemsetAsync(fc1a, 0, 256*128*sizeof(float), stream);
  for (int c = 0; c < NCH; c++){
    int t0f = c * CT, t0b = (NCH - 1 - c) * CT;
    k_gemm_chunk<512><<<dim3(CROWS/128, 6, 2), 256, 0, stream>>>(h1, P+PO_WIH1, P+PO_CB1, xprz, xpn, t0f, t0b);
    k_gru_chunk<<<32, 512, GRU_SMEM, stream>>>(xprz, xpn, P+PO_WHH1, P+PO_BHH1, hst, h2, h2b, 0, t0f, t0b);
    k_fc1_chunk<<<dim3(64, 2), 256, 0, stream>>>(h2, W1, flg+13, t0f, t0b, fc1a);
  }

  k_fc2<<<1, 256, 0, stream>>>(fc1a, P+PO_B1, P+PO_W2, P+PO_B2, flg, d_out);
}

// Round 11
// 5080.660 us; speedup vs baseline: 1.3452x; 1.1035x over previous
//
#include <hip/hip_runtime.h>
#include <hip/hip_bf16.h>
#include <stdint.h>

// Problem dims
#define BB 256
#define TT 512
#define EE 128
#define HH 256
#define MM (TT*BB)       // 131072 rows total
#define CT 32            // timesteps per chunk (halved: xp ping-pong memory-neutral)
#define NCH (TT/CT)      // 16 chunks
#define CROWS (CT*BB)    // 8192 rows per chunk
// swizzled xp sizes (shorts)
#define RZ_TL  131072    // 16bg*8w*64lane*16 shorts per tl slot per dir
#define RZ_DIR (CT*RZ_TL)        // 4194304
#define N_TL   65536
#define N_DIR  (CT*N_TL)         // 2097152
// byte sizes for ping-pong sets
#define XPSET_B  25165824ul      // (2*RZ_DIR + 2*N_DIR)*2 bytes per set
#define XPN_OFF_B 16777216ul     // rz part bytes within a set
#define H2SET_B  8388608ul       // CROWS*256*2dirs*2B per set
// GRU dynamic LDS: swizzled n-gate weights + h dbuf (same as proven round-6)
#define WN_SH   65536                 // shorts (128 KB)
#define HBUF_SH (16*264)              // shorts per buffer
#define GRU_SMEM ((WN_SH + 2*HBUF_SH) * 2)   // bytes = 147968 (<= 160K)

typedef __attribute__((ext_vector_type(8))) short bf16x8;
typedef __attribute__((ext_vector_type(4))) float f32x4;

__device__ __forceinline__ float bf2f(unsigned short u){
  union { unsigned int i; float f; } v; v.i = ((unsigned int)u) << 16; return v.f;
}
__device__ __forceinline__ unsigned short f2bf(float f){
  union { float f; unsigned int i; } v; v.f = f;
  unsigned int u = v.i;
  unsigned int r = (u + 0x7FFFu + ((u >> 16) & 1u)) >> 16;
  return (unsigned short)r;
}
__device__ __forceinline__ float sigm(float x){ return 1.f / (1.f + __expf(-x)); }
__device__ __forceinline__ float tanh_f(float x){
  float e2 = __expf(2.f * x);
  return 1.f - 2.f / (e2 + 1.f);
}

// -------- sentinel --------
__global__ void k_sentinel(unsigned short* out, float v){ out[threadIdx.x] = f2bf(v); }

// -------- dtype probe: is this float tensor fp32 (vs bf16)? --------
__global__ void k_probe_f(const unsigned short* __restrict__ buf, int n,
                          unsigned* __restrict__ flagw){
  __shared__ int cnt;
  if (threadIdx.x == 0) cnt = 0;
  __syncthreads();
  int scanw = n < 4096 ? n : 4096;
  int bad = 0;
  for (int i = threadIdx.x; i < scanw; i += 256){
    unsigned short u = buf[i];
    unsigned e = (u >> 7) & 0xFF;
    if (u != 0 && (e < 0x60 || e == 0xFF)) bad++;
  }
  atomicAdd(&cnt, bad);
  __syncthreads();
  if (threadIdx.x == 0) *flagw = (cnt * 8 > scanw) ? 1u : 0u;
}

// -------- int width probe: int64 iff odd int32 words are (almost) all zero --------
__global__ void k_probe_i(const int* __restrict__ buf, int n, unsigned* __restrict__ flagw){
  __shared__ int cnt;
  if (threadIdx.x == 0) cnt = 0;
  __syncthreads();
  int scan = n < 1024 ? n : 1024;
  int nz = 0;
  for (int i = threadIdx.x; i < scan; i += 256)
    if ((i & 1) && buf[i] != 0) nz++;
  atomicAdd(&cnt, nz);
  __syncthreads();
  if (threadIdx.x == 0) *flagw = (cnt < 10) ? 1u : 0u;
}

// -------- convert a float tensor (fp32 or bf16 per flag) to bf16 dst --------
__global__ __launch_bounds__(256) void k_convert(const void* __restrict__ src, int n,
                                                 const unsigned* __restrict__ flagw,
                                                 unsigned short* __restrict__ dst){
  int fp32 = (int)*flagw;
  int i0 = blockIdx.x * 256 + threadIdx.x;
  int stride = gridDim.x * 256;
  if (fp32){
    const float* s = (const float*)src;
    for (int i = i0; i < n; i += stride) dst[i] = f2bf(s[i]);
  } else {
    const unsigned short* s = (const unsigned short*)src;
    for (int i = i0; i < n; i += stride) dst[i] = s[i];
  }
}

// -------- combined bias: cb[dir][n] = b_ih[dir][n] + (n < 512 ? b_hh[dir][n] : 0) --------
// NOTE: 768 is NOT a power of two -- must use %, not & (round-1 bug).
__global__ __launch_bounds__(256) void k_prep_bias(const unsigned short* __restrict__ bih,
                                                   const unsigned short* __restrict__ bhh,
                                                   unsigned short* __restrict__ cb){
  int i = blockIdx.x * 256 + threadIdx.x;   // 0..1535 (2 dirs x 768)
  if (i >= 1536) return;
  int n = i % 768;
  float v = bf2f(bih[i]);
  if (n < 512) v += bf2f(bhh[i]);
  cb[i] = f2bf(v);
}

// ---------------- embed: x[t*B+b][e] = embc[inputs[b][t]][e] (bf16) ----------------
__global__ __launch_bounds__(256) void k_embed(const unsigned short* __restrict__ embc,
                                               const void* __restrict__ inputs,
                                               const unsigned* __restrict__ i64f,
                                               unsigned short* __restrict__ x){
  int c = blockIdx.x * 256 + threadIdx.x;  // 16B chunk id; total = MM*16
  int e8 = (c & 15) * 8;
  int tb = c >> 4;
  int t = tb >> 8;
  int b = tb & 255;
  long k = (long)b * TT + t;
  int idx = (*i64f) ? ((const int*)inputs)[k * 2] : ((const int*)inputs)[k];
  idx = idx < 0 ? 0 : (idx > 64 ? 64 : idx);
  *(bf16x8*)(x + (long)tb * EE + e8) = *(const bf16x8*)(embc + (long)idx * EE + e8);
}

// ================== FUSED CHUNK KERNEL: GRU(c) || GEMM(c+1) || FC1(c-1) ==================
// OccupancyPercent was 2.9% during GRU (32 blocks on 256 CUs) while GEMM/fc1 ran
// SERIALIZED on the stream. This kernel co-schedules the independent work:
//   blocks [0,32)            : GRU role, chunk c   (reads xp set (c)&1, proven round-6 code)
//   blocks [32, 32+n_gemm)   : GEMM role, chunk c+1 (writes xp set (c+1)&1)
//   blocks [.., +32)         : FC1 role, chunk c-1  (reads h2 set (c-1)&1; GRU writes (c)&1)
// All roles are data-independent within one launch; cross-launch deps are stream-ordered.
// CT=32 makes the xp/h2 ping-pong fit the OLD memory footprint exactly.
// All blocks are 512 threads with 145KB dynamic LDS (GRU's requirement; 1 block/CU).
__global__ __attribute__((amdgpu_flat_work_group_size(512, 512), amdgpu_waves_per_eu(2, 2)))
void k_fused(// gemm role
             const unsigned short* __restrict__ A, const unsigned short* __restrict__ W,
             const unsigned short* __restrict__ bias,
             unsigned short* __restrict__ xprz_w, unsigned short* __restrict__ xpn_w,
             int K, int g_t0f, int g_t0b, int n_gemm,
             // gru role
             const unsigned short* __restrict__ xprz_r, const unsigned short* __restrict__ xpn_r,
             const unsigned short* __restrict__ whh, const unsigned short* __restrict__ bhh,
             float* __restrict__ hstate,
             unsigned short* __restrict__ outf, unsigned short* __restrict__ outb,
             int out_full, int r_t0f, int r_t0b, int has_gru,
             // fc1 role
             const unsigned short* __restrict__ h2r, const void* __restrict__ W1,
             const unsigned* __restrict__ w1f, float* __restrict__ fc1acc,
             int f_t0f, int f_t0b, int has_fc1)
{
  extern __shared__ __align__(16) unsigned short smem[];
  int bid = blockIdx.x;
  int tid = threadIdx.x;

  // ---------------- GRU role (round-6 proven structure, unchanged) ----------------
  if (has_gru && bid < 32){
    unsigned short* wn_lds = smem;
    unsigned short* hbuf   = smem + WN_SH;

    int dir = bid >> 4;
    int bg  = bid & 15;
    int b0  = bg * 16;
    int wave = tid >> 6, lane = tid & 63;
    int ln16 = lane & 15, quad = lane >> 4;
    unsigned short* outp = dir ? outb : outf;
    int t0 = dir ? r_t0b : r_t0f;

    const unsigned short* rzbase = xprz_r + (long)dir * RZ_DIR + ((long)(bg*8 + wave)*64 + lane) * 16;
    const unsigned short* nbase  = xpn_r  + (long)dir * N_DIR  + ((long)(bg*8 + wave)*64 + lane) * 8;

    // stage n-gate weights into LDS, fragment-major (conflict-free ds_read_b128)
    for (int v = tid; v < 256*32; v += 512){
      int c = v >> 5, j = v & 31;
      int g = c >> 4, l16 = c & 15;
      int kt = j >> 2, qd = j & 3;
      *(bf16x8*)&wn_lds[(((g*8 + kt)*64) + qd*16 + l16) * 8] =
        *(const bf16x8*)&whh[((long)(dir*768 + 512 + c))*256 + j*8];
    }

    // r,z weight fragments register-resident (128 VGPR), laundered
    bf16x8 wr[2][8], wz[2][8];
    #pragma unroll
    for (int i = 0; i < 2; i++){
      int c = (wave*2 + i)*16 + ln16;
      const unsigned short* Wb = whh + ((long)(dir*768 + c)) * 256 + quad*8;
      #pragma unroll
      for (int kt = 0; kt < 8; kt++){
        wr[i][kt] = *(const bf16x8*)(Wb + kt*32);
        wz[i][kt] = *(const bf16x8*)(Wb + 256*256 + kt*32);
        asm volatile("" : "+v"(wr[i][kt]), "+v"(wz[i][kt]));
      }
    }

    float h_old[2][4];
    #pragma unroll
    for (int i = 0; i < 2; i++){
      int c = (wave*2 + i)*16 + ln16;
      #pragma unroll
      for (int r = 0; r < 4; r++){
        int b = quad*4 + r;
        float hv = hstate[((long)dir*256 + b0 + b)*256 + c];
        h_old[i][r] = hv;
        hbuf[b * 264 + c] = f2bf(hv);
      }
    }
    float bh_n[2];
    #pragma unroll
    for (int i = 0; i < 2; i++){
      int c = (wave*2 + i)*16 + ln16;
      bh_n[i] = bf2f(bhh[dir*768 + 512 + c]);
    }

    int wnb0 = ((wave*2 + 0)*8)*64*8 + lane*8;
    int wnb1 = ((wave*2 + 1)*8)*64*8 + lane*8;

    int tl = dir ? (CT-1) : 0;
    bf16x8 c_rz0 = *(const bf16x8*)(rzbase + (long)tl*RZ_TL);
    bf16x8 c_rz1 = *(const bf16x8*)(rzbase + (long)tl*RZ_TL + 8);
    bf16x8 c_n   = *(const bf16x8*)(nbase  + (long)tl*N_TL);
    __syncthreads();

    int p = 0;
    for (int ss = 0; ss < CT; ss++){
      int tln = (ss == CT-1) ? tl : (dir ? tl-1 : tl+1);

      unsigned short* hb_cur = hbuf + p*HBUF_SH;
      unsigned short* hb_nxt = hbuf + (1-p)*HBUF_SH;

      f32x4 ar[2], az[2], an[2];
      #pragma unroll
      for (int i = 0; i < 2; i++){
        ar[i] = (f32x4){0.f,0.f,0.f,0.f};
        az[i] = (f32x4){0.f,0.f,0.f,0.f};
        an[i] = (f32x4){0.f,0.f,0.f,0.f};
      }

      bf16x8 afb[2], wnb[2][2];
      afb[0]    = *(bf16x8*)&hb_cur[ln16*264 + quad*8];
      wnb[0][0] = *(bf16x8*)&wn_lds[wnb0];
      wnb[0][1] = *(bf16x8*)&wn_lds[wnb1];
      #pragma unroll
      for (int kt = 0; kt < 8; kt++){
        int cur = kt & 1, nxt = cur ^ 1;
        if (kt < 7){
          afb[nxt]    = *(bf16x8*)&hb_cur[ln16*264 + (kt+1)*32 + quad*8];
          wnb[nxt][0] = *(bf16x8*)&wn_lds[wnb0 + (kt+1)*64*8];
          wnb[nxt][1] = *(bf16x8*)&wn_lds[wnb1 + (kt+1)*64*8];
        }
        ar[0] = __builtin_amdgcn_mfma_f32_16x16x32_bf16(afb[cur], wr[0][kt], ar[0], 0, 0, 0);
        az[0] = __builtin_amdgcn_mfma_f32_16x16x32_bf16(afb[cur], wz[0][kt], az[0], 0, 0, 0);
        an[0] = __builtin_amdgcn_mfma_f32_16x16x32_bf16(afb[cur], wnb[cur][0], an[0], 0, 0, 0);
        ar[1] = __builtin_amdgcn_mfma_f32_16x16x32_bf16(afb[cur], wr[1][kt], ar[1], 0, 0, 0);
        az[1] = __builtin_amdgcn_mfma_f32_16x16x32_bf16(afb[cur], wz[1][kt], az[1], 0, 0, 0);
        an[1] = __builtin_amdgcn_mfma_f32_16x16x32_bf16(afb[cur], wnb[cur][1], an[1], 0, 0, 0);
      }

      bf16x8 n_rz0 = *(const bf16x8*)(rzbase + (long)tln*RZ_TL);
      bf16x8 n_rz1 = *(const bf16x8*)(rzbase + (long)tln*RZ_TL + 8);
      bf16x8 n_n   = *(const bf16x8*)(nbase  + (long)tln*N_TL);

      #pragma unroll
      for (int i = 0; i < 2; i++){
        int c = (wave*2 + i)*16 + ln16;
        #pragma unroll
        for (int r = 0; r < 4; r++){
          float xr = bf2f((unsigned short)(i ? c_rz1[r]   : c_rz0[r]));
          float xz = bf2f((unsigned short)(i ? c_rz1[4+r] : c_rz0[4+r]));
          float xn = bf2f((unsigned short)c_n[i*4 + r]);
          float rg = sigm(xr + ar[i][r]);
          float zg = sigm(xz + az[i][r]);
          float ng = tanh_f(xn + rg * (an[i][r] + bh_n[i]));
          float hnew = (1.f - zg) * ng + zg * h_old[i][r];
          h_old[i][r] = hnew;
          unsigned short hb = f2bf(hnew);
          int b = b0 + quad*4 + r;
          hb_nxt[(quad*4 + r) * 264 + c] = hb;
          long oidx = out_full ? (((long)(t0 + tl) * 256 + b) * 512 + dir*256 + c)
                               : (((long)tl * 256 + b) * 256 + c);
          outp[oidx] = hb;
        }
      }
      __syncthreads();
      p ^= 1;
      tl = tln;
      c_rz0 = n_rz0; c_rz1 = n_rz1; c_n = n_n;
    }

    #pragma unroll
    for (int i = 0; i < 2; i++){
      int c = (wave*2 + i)*16 + ln16;
      #pragma unroll
      for (int r = 0; r < 4; r++)
        hstate[((long)dir*256 + b0 + quad*4 + r)*256 + c] = h_old[i][r];
    }
    return;
  }

  int gb = bid - (has_gru ? 32 : 0);

  // ---------------- GEMM role (two 128-wide n0 tiles per 512-thr block) ----------------
  if (gb < n_gemm){
    int half = tid >> 8, tq = tid & 255;
    int bx = gb & 63;               // m0 tile: CROWS/128 = 64
    int rest = gb >> 6;             // 0..5
    int by = rest % 3, gdir = rest / 3;
    const unsigned short* Ad = A + (long)(gdir ? g_t0b : g_t0f) * 256 * K;
    const unsigned short* Wd = W + (long)gdir * 768 * K;
    const unsigned short* bd = bias + gdir * 768;
    unsigned short* rzd = xprz_w + (long)gdir * RZ_DIR;
    unsigned short* nd  = xpn_w  + (long)gdir * N_DIR;
    unsigned short* As = smem;                       // 9216 shorts
    unsigned short* Bs = smem + 9216 + half*9216;    // per-half B tile

    long m0 = (long)bx * 128;
    int  n0 = (by*2 + half) * 128;
    int wave = tq >> 6, lane = tq & 63;
    int wm = (wave & 1) * 64, wn = (wave >> 1) * 64;
    int ln16 = lane & 15, quad = lane >> 4;
    f32x4 acc[4][4];
    #pragma unroll
    for (int i = 0; i < 4; i++)
      #pragma unroll
      for (int j = 0; j < 4; j++) acc[i][j] = (f32x4){0.f,0.f,0.f,0.f};

    for (int k0 = 0; k0 < K; k0 += 64){
      #pragma unroll
      for (int i = 0; i < 4; i++){
        int cc = tq + 256 * i;      // 1024 chunks of 8 bf16
        int row = cc >> 3, koff = (cc & 7) * 8;
        if (half == 0)
          *(bf16x8*)&As[row * 72 + koff] = *(const bf16x8*)&Ad[(m0 + row) * K + k0 + koff];
        *(bf16x8*)&Bs[row * 72 + koff] = *(const bf16x8*)&Wd[(long)(n0 + row) * K + k0 + koff];
      }
      __syncthreads();
      #pragma unroll
      for (int kk = 0; kk < 64; kk += 32){
        bf16x8 af[4], bfr[4];
        #pragma unroll
        for (int mi = 0; mi < 4; mi++) af[mi]  = *(bf16x8*)&As[(wm + mi*16 + ln16) * 72 + kk + quad*8];
        #pragma unroll
        for (int nj = 0; nj < 4; nj++) bfr[nj] = *(bf16x8*)&Bs[(wn + nj*16 + ln16) * 72 + kk + quad*8];
        #pragma unroll
        for (int mi = 0; mi < 4; mi++)
          #pragma unroll
          for (int nj = 0; nj < 4; nj++)
            acc[mi][nj] = __builtin_amdgcn_mfma_f32_16x16x32_bf16(af[mi], bfr[nj], acc[mi][nj], 0, 0, 0);
      }
      __syncthreads();
    }
    // swizzled epilogue
    #pragma unroll
    for (int mi = 0; mi < 4; mi++)
      #pragma unroll
      for (int nj = 0; nj < 4; nj++){
        int n = n0 + wn + nj*16 + ln16;       // 0..767 within dir
        int g = n >> 8, cc = n & 255;
        int w = cc >> 5, ii = (cc >> 4) & 1;
        float bv = bf2f(bd[n]);
        #pragma unroll
        for (int r = 0; r < 4; r++){
          long m = m0 + wm + mi*16 + quad*4 + r;
          int tl = (int)(m >> 8);
          int bgx = ((int)m & 255) >> 4;
          long rec = (((long)tl*16 + bgx)*8 + w)*64 + quad*16 + ln16;
          unsigned short val = f2bf(acc[mi][nj][r] + bv);
          if (g < 2) rzd[rec*16 + ii*8 + g*4 + r] = val;
          else       nd [rec*8  + ii*4 + r]       = val;
        }
      }
    return;
  }

  // ---------------- FC1 role (two (mb,kb,dir) units per 512-thr block) ----------------
  if (has_fc1){
    int fb = gb - n_gemm;           // 0..31
    if (fb >= 32) return;
    int half = tid >> 8, tq = tid & 255;
    int unit = fb*2 + half;         // 0..63
    int fdir = unit >> 5;
    int u = unit & 31;
    int mb = u & 3, kb = u >> 2;    // kb 0..7
    const unsigned short* h2d = h2r + (long)fdir * CROWS * 256;
    int t0 = fdir ? f_t0b : f_t0f;
    int dircol = fdir * 256;
    int wave = tq >> 6, lane = tq & 63;
    int ln16 = lane & 15, quad = lane >> 4;
    int w1fp32 = (int)*w1f;
    f32x4 acc[8];
    #pragma unroll
    for (int nt = 0; nt < 8; nt++) acc[nt] = (f32x4){0.f,0.f,0.f,0.f};

    for (int tt = 0; tt < 4; tt++){
      int tl = kb*4 + tt;           // 0..31
      const unsigned short* Ah = h2d + ((long)tl * 256 + mb*64 + wave*16) * 256;
      long bbase = (long)(t0 + tl) * 512 + dircol;
      #pragma unroll
      for (int kt = 0; kt < 8; kt++){
        bf16x8 af = *(const bf16x8*)(Ah + (long)ln16*256 + kt*32 + quad*8);
        #pragma unroll
        for (int nt = 0; nt < 8; nt++){
          long off = bbase + (long)(nt*16 + ln16)*262144 + kt*32 + quad*8;
          bf16x8 bfr;
          if (w1fp32){
            const float* pp = (const float*)W1 + off;
            #pragma unroll
            for (int j = 0; j < 8; j++) bfr[j] = (short)f2bf(pp[j]);
          } else {
            bfr = *(const bf16x8*)((const unsigned short*)W1 + off);
          }
          acc[nt] = __builtin_amdgcn_mfma_f32_16x16x32_bf16(af, bfr, acc[nt], 0, 0, 0);
        }
      }
    }
    #pragma unroll
    for (int nt = 0; nt < 8; nt++)
      #pragma unroll
      for (int r = 0; r < 4; r++){
        int m = mb*64 + wave*16 + quad*4 + r;
        int n = nt*16 + ln16;
        atomicAdd(&fc1acc[m*128 + n], acc[nt][r]);
      }
  }
}

// ------- final: leaky_relu(fc1acc + b1) @ W2 + b2 -> sigmoid -------
__global__ __launch_bounds__(256) void k_fc2(const float* __restrict__ fc1acc,
                                             const unsigned short* __restrict__ b1,
                                             const unsigned short* __restrict__ W2,
                                             const unsigned short* __restrict__ b2,
                                             const unsigned* __restrict__ flags,
                                             void* __restrict__ out){
  int b = threadIdx.x;
  float s = bf2f(b2[0]);
  for (int j = 0; j < 128; j++){
    float v = fc1acc[b*128 + j] + bf2f(b1[j]);
    v = v > 0.f ? v : 0.01f * v;
    s += v * bf2f(W2[j]);
  }
  float r = sigm(s);
  if (flags[1]) ((float*)out)[b] = r;          // fp32 world -> fp32 output
  else          ((unsigned short*)out)[b] = f2bf(r);
}

extern "C" void kernel_launch(void* const* d_in, const int* in_sizes, int n_in,
                              void* d_out, int out_size, void* d_ws, size_t ws_size,
                              hipStream_t stream) {
  const void* inp  = d_in[0];
  const void* emb  = d_in[1];
  const void* wih0 = d_in[2];
  const void* whh0 = d_in[3];
  const void* bih0 = d_in[4];
  const void* bhh0 = d_in[5];
  const void* wih1 = d_in[6];
  const void* whh1 = d_in[7];
  const void* bih1 = d_in[8];
  const void* bhh1 = d_in[9];
  const void* W1   = d_in[10];
  const void* b1   = d_in[11];
  const void* W2   = d_in[12];
  const void* b2   = d_in[13];
  unsigned short* out = (unsigned short*)d_out;

  const int expect[14] = {131072, 8320, 196608, 393216, 1536, 1536,
                          786432, 393216, 1536, 1536, 33554432, 128, 128, 1};
  for (int i = 0; i < 14 && i < n_in; i++){
    if (in_sizes[i] != expect[i]){
      k_sentinel<<<1, 256, 0, stream>>>(out, 4.0f * (600.0f + i));
      return;
    }
  }

  // dynamic LDS attr (idempotent host-side attr, not a stream op; 145 KB)
  static int smem_set = 0;
  if (!smem_set){
    hipFuncSetAttribute((const void*)k_fused,
                        hipFuncAttributeMaxDynamicSharedMemorySize, GRU_SMEM);
    smem_set = 1;
  }

  // workspace layout (bytes) -- total footprint IDENTICAL to previous rounds
  const size_t OFF_X    = 0;                       // x    [131072*128] bf16 (33.5 MB)
  const size_t OFF_H1   = 33554432ul;              // h1   [131072*512] bf16 (134 MB)
  const size_t OFF_XP   = 167772160ul;             // xp ping-pong: 2 sets x 25.2 MB
  const size_t OFF_H2   = 218103808ul;             // h2 ping-pong: 2 sets x 8.4 MB
  const size_t OFF_ST   = 234881024ul;             // hstate [2*256*256] f32
  const size_t OFF_FC   = 235405312ul;             // fc1acc [256*128] f32
  const size_t OFF_FLAG = 235536384ul;             // 16 flag words
  const size_t OFF_P    = 235536448ul;             // converted bf16 params (~3.6 MB)
  unsigned short* P;
  const size_t PO_EMB  = 0;        // 8320
  const size_t PO_WIH0 = 8320;     // 196608
  const size_t PO_WHH0 = 204928;   // 393216
  const size_t PO_BIH0 = 598144;   // 1536
  const size_t PO_BHH0 = 599680;   // 1536
  const size_t PO_WIH1 = 601216;   // 786432
  const size_t PO_WHH1 = 1387648;  // 393216
  const size_t PO_BIH1 = 1780864;  // 1536
  const size_t PO_BHH1 = 1782400;  // 1536
  const size_t PO_B1   = 1783936;  // 128
  const size_t PO_W2   = 1784064;  // 128
  const size_t PO_B2   = 1784192;  // 1 (+pad)
  const size_t PO_CB0  = 1784200;  // combined bias layer0 [2*768]
  const size_t PO_CB1  = 1785736;  // combined bias layer1 [2*768]
  const size_t NEED    = OFF_P + 2*(1785736ul + 1536ul);

  if (ws_size < NEED) {
    k_sentinel<<<1, 256, 0, stream>>>(out, (float)(ws_size >> 20));
    return;
  }

  char* ws = (char*)d_ws;
  unsigned short* x    = (unsigned short*)(ws + OFF_X);
  unsigned short* h1   = (unsigned short*)(ws + OFF_H1);
  float*          hst  = (float*)(ws + OFF_ST);
  float*          fc1a = (float*)(ws + OFF_FC);
  unsigned*       flg  = (unsigned*)(ws + OFF_FLAG);
  P = (unsigned short*)(ws + OFF_P);

  hipMemsetAsync(flg, 0, 64, stream);

  // ---- dtype probes ----
  k_probe_f<<<1,256,0,stream>>>((const unsigned short*)emb,  8320,     flg+1);
  k_probe_f<<<1,256,0,stream>>>((const unsigned short*)wih0, 196608,   flg+2);
  k_probe_f<<<1,256,0,stream>>>((const unsigned short*)whh0, 393216,   flg+3);
  k_probe_f<<<1,256,0,stream>>>((const unsigned short*)bih0, 1536,     flg+4);
  k_probe_f<<<1,256,0,stream>>>((const unsigned short*)bhh0, 1536,     flg+5);
  k_probe_f<<<1,256,0,stream>>>((const unsigned short*)wih1, 786432,   flg+6);
  k_probe_f<<<1,256,0,stream>>>((const unsigned short*)whh1, 393216,   flg+7);
  k_probe_f<<<1,256,0,stream>>>((const unsigned short*)bih1, 1536,     flg+8);
  k_probe_f<<<1,256,0,stream>>>((const unsigned short*)bhh1, 1536,     flg+9);
  k_probe_f<<<1,256,0,stream>>>((const unsigned short*)b1,   128,      flg+10);
  k_probe_f<<<1,256,0,stream>>>((const unsigned short*)W2,   128,      flg+11);
  k_probe_f<<<1,256,0,stream>>>((const unsigned short*)b2,   1,        flg+12);
  k_probe_f<<<1,256,0,stream>>>((const unsigned short*)W1,   33554432, flg+13);
  k_probe_i<<<1,256,0,stream>>>((const int*)inp, 131072, flg+14);

  // ---- convert params to bf16 ----
  k_convert<<<64,256,0,stream>>>(emb,  8320,   flg+1,  P+PO_EMB);
  k_convert<<<64,256,0,stream>>>(wih0, 196608, flg+2,  P+PO_WIH0);
  k_convert<<<64,256,0,stream>>>(whh0, 393216, flg+3,  P+PO_WHH0);
  k_convert<<<8, 256,0,stream>>>(bih0, 1536,   flg+4,  P+PO_BIH0);
  k_convert<<<8, 256,0,stream>>>(bhh0, 1536,   flg+5,  P+PO_BHH0);
  k_convert<<<64,256,0,stream>>>(wih1, 786432, flg+6,  P+PO_WIH1);
  k_convert<<<64,256,0,stream>>>(whh1, 393216, flg+7,  P+PO_WHH1);
  k_convert<<<8, 256,0,stream>>>(bih1, 1536,   flg+8,  P+PO_BIH1);
  k_convert<<<8, 256,0,stream>>>(bhh1, 1536,   flg+9,  P+PO_BHH1);
  k_convert<<<1, 256,0,stream>>>(b1,   128,    flg+10, P+PO_B1);
  k_convert<<<1, 256,0,stream>>>(W2,   128,    flg+11, P+PO_W2);
  k_convert<<<1, 256,0,stream>>>(b2,   1,      flg+12, P+PO_B2);

  // ---- combined biases (b_ih + b_hh for r,z gates) ----
  k_prep_bias<<<6,256,0,stream>>>(P+PO_BIH0, P+PO_BHH0, P+PO_CB0);
  k_prep_bias<<<6,256,0,stream>>>(P+PO_BIH1, P+PO_BHH1, P+PO_CB1);

  k_embed<<<MM*16/256, 256, 0, stream>>>(P+PO_EMB, inp, flg+14, x);

  // ---- layer 0: pipeline { gemm(c) } with { gru(c-1) } ----
  hipMemsetAsync(hst, 0, 2*256*256*sizeof(float), stream);
  for (int c = 0; c <= NCH; c++){
    int has_g = (c < NCH);
    int has_r = (c > 0);
    unsigned short* xprz_w = (unsigned short*)(ws + OFF_XP + (size_t)(c & 1)*XPSET_B);
    unsigned short* xpn_w  = (unsigned short*)(ws + OFF_XP + (size_t)(c & 1)*XPSET_B + XPN_OFF_B);
    unsigned short* xprz_r = (unsigned short*)(ws + OFF_XP + (size_t)((c-1) & 1)*XPSET_B);
    unsigned short* xpn_r  = (unsigned short*)(ws + OFF_XP + (size_t)((c-1) & 1)*XPSET_B + XPN_OFF_B);
    int gt0f = c*CT, gt0b = (NCH-1-c)*CT;
    int rt0f = (c-1)*CT, rt0b = (NCH-c)*CT;
    int n_gemm = has_g ? 384 : 0;
    int grid = (has_r ? 32 : 0) + n_gemm;
    k_fused<<<grid, 512, GRU_SMEM, stream>>>(
        x, P+PO_WIH0, P+PO_CB0, xprz_w, xpn_w, 128, gt0f, gt0b, n_gemm,
        xprz_r, xpn_r, P+PO_WHH0, P+PO_BHH0, hst, h1, h1, 1, rt0f, rt0b, has_r,
        (const unsigned short*)nullptr, (const void*)nullptr,
        (const unsigned*)nullptr, (float*)nullptr, 0, 0, 0);
  }

  // ---- layer 1: pipeline { gemm(c) } with { gru(c-1) } with { fc1(c-2) } ----
  hipMemsetAsync(hst, 0, 2*256*256*sizeof(float), stream);
  hipMemsetAsync(fc1a, 0, 256*128*sizeof(float), stream);
  for (int c = 0; c <= NCH+1; c++){
    int has_g = (c < NCH);
    int has_r = (c >= 1 && c <= NCH);
    int has_f = (c >= 2);
    unsigned short* xprz_w = (unsigned short*)(ws + OFF_XP + (size_t)(c & 1)*XPSET_B);
    unsigned short* xpn_w  = (unsigned short*)(ws + OFF_XP + (size_t)(c & 1)*XPSET_B + XPN_OFF_B);
    unsigned short* xprz_r = (unsigned short*)(ws + OFF_XP + (size_t)((c-1) & 1)*XPSET_B);
    unsigned short* xpn_r  = (unsigned short*)(ws + OFF_XP + (size_t)((c-1) & 1)*XPSET_B + XPN_OFF_B);
    unsigned short* h2w = (unsigned short*)(ws + OFF_H2 + (size_t)((c-1) & 1)*H2SET_B);
    unsigned short* h2r = (unsigned short*)(ws + OFF_H2 + (size_t)((c-2) & 1)*H2SET_B);
    int gt0f = c*CT, gt0b = (NCH-1-c)*CT;
    int rt0f = (c-1)*CT, rt0b = (NCH-c)*CT;
    int ft0f = (c-2)*CT, ft0b = (NCH+1-c)*CT;
    int n_gemm = has_g ? 384 : 0;
    int grid = (has_r ? 32 : 0) + n_gemm + (has_f ? 32 : 0);
    if (grid == 0) continue;
    k_fused<<<grid, 512, GRU_SMEM, stream>>>(
        h1, P+PO_WIH1, P+PO_CB1, xprz_w, xpn_w, 512, gt0f, gt0b, n_gemm,
        xprz_r, xpn_r, P+PO_WHH1, P+PO_BHH1, hst,
        h2w, h2w + (long)CROWS*256, 0, rt0f, rt0b, has_r,
        h2r, W1, flg+13, fc1a, ft0f, ft0b, has_f);
  }

  k_fc2<<<1, 256, 0, stream>>>(fc1a, P+PO_B1, P+PO_W2, P+PO_B2, flg, d_out);
}

// Round 12
// 5031.670 us; speedup vs baseline: 1.3583x; 1.0097x over previous
//
#include <hip/hip_runtime.h>
#include <hip/hip_bf16.h>
#include <stdint.h>

// Problem dims
#define BB 256
#define TT 512
#define EE 128
#define HH 256
#define MM (TT*BB)       // 131072 rows total
#define CT 32            // timesteps per chunk (xp ping-pong memory-neutral)
#define NCH (TT/CT)      // 16 chunks
#define CROWS (CT*BB)    // 8192 rows per chunk
// swizzled xp sizes (shorts)
#define RZ_TL  131072    // 16bg*8w*64lane*16 shorts per tl slot per dir
#define RZ_DIR (CT*RZ_TL)        // 4194304
#define N_TL   65536
#define N_DIR  (CT*N_TL)         // 2097152
// byte sizes for ping-pong sets
#define XPSET_B  25165824ul      // (2*RZ_DIR + 2*N_DIR)*2 bytes per set
#define XPN_OFF_B 16777216ul     // rz part bytes within a set
#define H2SET_B  8388608ul       // CROWS*256*2dirs*2B per set
// GRU dynamic LDS: swizzled n-gate weights + h dbuf (same as proven round-6)
#define WN_SH   65536                 // shorts (128 KB)
#define HBUF_SH (16*264)              // shorts per buffer
#define GRU_SMEM ((WN_SH + 2*HBUF_SH) * 2)   // bytes = 147968 (<= 160K)

typedef __attribute__((ext_vector_type(8))) short bf16x8;
typedef __attribute__((ext_vector_type(4))) float f32x4;

__device__ __forceinline__ float bf2f(unsigned short u){
  union { unsigned int i; float f; } v; v.i = ((unsigned int)u) << 16; return v.f;
}
__device__ __forceinline__ unsigned short f2bf(float f){
  union { float f; unsigned int i; } v; v.f = f;
  unsigned int u = v.i;
  unsigned int r = (u + 0x7FFFu + ((u >> 16) & 1u)) >> 16;
  return (unsigned short)r;
}
__device__ __forceinline__ float sigm(float x){ return 1.f / (1.f + __expf(-x)); }
__device__ __forceinline__ float tanh_f(float x){
  float e2 = __expf(2.f * x);
  return 1.f - 2.f / (e2 + 1.f);
}

// -------- sentinel --------
__global__ void k_sentinel(unsigned short* out, float v){ out[threadIdx.x] = f2bf(v); }

// -------- dtype probe: is this float tensor fp32 (vs bf16)? --------
__global__ void k_probe_f(const unsigned short* __restrict__ buf, int n,
                          unsigned* __restrict__ flagw){
  __shared__ int cnt;
  if (threadIdx.x == 0) cnt = 0;
  __syncthreads();
  int scanw = n < 4096 ? n : 4096;
  int bad = 0;
  for (int i = threadIdx.x; i < scanw; i += 256){
    unsigned short u = buf[i];
    unsigned e = (u >> 7) & 0xFF;
    if (u != 0 && (e < 0x60 || e == 0xFF)) bad++;
  }
  atomicAdd(&cnt, bad);
  __syncthreads();
  if (threadIdx.x == 0) *flagw = (cnt * 8 > scanw) ? 1u : 0u;
}

// -------- int width probe: int64 iff odd int32 words are (almost) all zero --------
__global__ void k_probe_i(const int* __restrict__ buf, int n, unsigned* __restrict__ flagw){
  __shared__ int cnt;
  if (threadIdx.x == 0) cnt = 0;
  __syncthreads();
  int scan = n < 1024 ? n : 1024;
  int nz = 0;
  for (int i = threadIdx.x; i < scan; i += 256)
    if ((i & 1) && buf[i] != 0) nz++;
  atomicAdd(&cnt, nz);
  __syncthreads();
  if (threadIdx.x == 0) *flagw = (cnt < 10) ? 1u : 0u;
}

// -------- convert a float tensor (fp32 or bf16 per flag) to bf16 dst --------
__global__ __launch_bounds__(256) void k_convert(const void* __restrict__ src, int n,
                                                 const unsigned* __restrict__ flagw,
                                                 unsigned short* __restrict__ dst){
  int fp32 = (int)*flagw;
  int i0 = blockIdx.x * 256 + threadIdx.x;
  int stride = gridDim.x * 256;
  if (fp32){
    const float* s = (const float*)src;
    for (int i = i0; i < n; i += stride) dst[i] = f2bf(s[i]);
  } else {
    const unsigned short* s = (const unsigned short*)src;
    for (int i = i0; i < n; i += stride) dst[i] = s[i];
  }
}

// -------- combined bias: cb[dir][n] = b_ih[dir][n] + (n < 512 ? b_hh[dir][n] : 0) --------
// NOTE: 768 is NOT a power of two -- must use %, not & (round-1 bug).
__global__ __launch_bounds__(256) void k_prep_bias(const unsigned short* __restrict__ bih,
                                                   const unsigned short* __restrict__ bhh,
                                                   unsigned short* __restrict__ cb){
  int i = blockIdx.x * 256 + threadIdx.x;   // 0..1535 (2 dirs x 768)
  if (i >= 1536) return;
  int n = i % 768;
  float v = bf2f(bih[i]);
  if (n < 512) v += bf2f(bhh[i]);
  cb[i] = f2bf(v);
}

// ---------------- embed: x[t*B+b][e] = embc[inputs[b][t]][e] (bf16) ----------------
__global__ __launch_bounds__(256) void k_embed(const unsigned short* __restrict__ embc,
                                               const void* __restrict__ inputs,
                                               const unsigned* __restrict__ i64f,
                                               unsigned short* __restrict__ x){
  int c = blockIdx.x * 256 + threadIdx.x;  // 16B chunk id; total = MM*16
  int e8 = (c & 15) * 8;
  int tb = c >> 4;
  int t = tb >> 8;
  int b = tb & 255;
  long k = (long)b * TT + t;
  int idx = (*i64f) ? ((const int*)inputs)[k * 2] : ((const int*)inputs)[k];
  idx = idx < 0 ? 0 : (idx > 64 ? 64 : idx);
  *(bf16x8*)(x + (long)tb * EE + e8) = *(const bf16x8*)(embc + (long)idx * EE + e8);
}

// ================== FUSED CHUNK KERNEL: GRU(c) || GEMM(c+1) || FC1(c-1) ==================
// ROUND-11 POST-MORTEM: fusion cut total 5606->5081, but the fused dispatch is
// GRU-tail-dominated: 194us for CT=32 (GRU per-step DOUBLED to ~6us under fusion;
// occupancy 9% = GEMM/fc1 finish early, GRU runs alone for the tail).
// Mechanism: __syncthreads in the GRU loop emits `s_waitcnt vmcnt(0)` -- round-10
// proved that drain NULL when uncontended, but under the GEMM role's ~450GB/s
// L2/HBM traffic the GRU's 8 scattered h-stores/step queue up and the full drain
// serializes their elevated latency into every step.
// ROUND-12 SINGLE-VARIABLE FIX: GRU-role in-loop barrier -> lgkmcnt-only counted
// barrier (round-10's construct: proven numerically safe, standalone-null).
// Stores/loads stay in flight across the barrier; only LDS (h dbuf) is ordered.
__global__ __attribute__((amdgpu_flat_work_group_size(512, 512), amdgpu_waves_per_eu(2, 2)))
void k_fused(// gemm role
             const unsigned short* __restrict__ A, const unsigned short* __restrict__ W,
             const unsigned short* __restrict__ bias,
             unsigned short* __restrict__ xprz_w, unsigned short* __restrict__ xpn_w,
             int K, int g_t0f, int g_t0b, int n_gemm,
             // gru role
             const unsigned short* __restrict__ xprz_r, const unsigned short* __restrict__ xpn_r,
             const unsigned short* __restrict__ whh, const unsigned short* __restrict__ bhh,
             float* __restrict__ hstate,
             unsigned short* __restrict__ outf, unsigned short* __restrict__ outb,
             int out_full, int r_t0f, int r_t0b, int has_gru,
             // fc1 role
             const unsigned short* __restrict__ h2r, const void* __restrict__ W1,
             const unsigned* __restrict__ w1f, float* __restrict__ fc1acc,
             int f_t0f, int f_t0b, int has_fc1)
{
  extern __shared__ __align__(16) unsigned short smem[];
  int bid = blockIdx.x;
  int tid = threadIdx.x;

  // ---------------- GRU role (round-6 structure + round-10 counted barrier) ----------------
  if (has_gru && bid < 32){
    unsigned short* wn_lds = smem;
    unsigned short* hbuf   = smem + WN_SH;

    int dir = bid >> 4;
    int bg  = bid & 15;
    int b0  = bg * 16;
    int wave = tid >> 6, lane = tid & 63;
    int ln16 = lane & 15, quad = lane >> 4;
    unsigned short* outp = dir ? outb : outf;
    int t0 = dir ? r_t0b : r_t0f;

    const unsigned short* rzbase = xprz_r + (long)dir * RZ_DIR + ((long)(bg*8 + wave)*64 + lane) * 16;
    const unsigned short* nbase  = xpn_r  + (long)dir * N_DIR  + ((long)(bg*8 + wave)*64 + lane) * 8;

    // stage n-gate weights into LDS, fragment-major (conflict-free ds_read_b128)
    for (int v = tid; v < 256*32; v += 512){
      int c = v >> 5, j = v & 31;
      int g = c >> 4, l16 = c & 15;
      int kt = j >> 2, qd = j & 3;
      *(bf16x8*)&wn_lds[(((g*8 + kt)*64) + qd*16 + l16) * 8] =
        *(const bf16x8*)&whh[((long)(dir*768 + 512 + c))*256 + j*8];
    }

    // r,z weight fragments register-resident (128 VGPR), laundered
    bf16x8 wr[2][8], wz[2][8];
    #pragma unroll
    for (int i = 0; i < 2; i++){
      int c = (wave*2 + i)*16 + ln16;
      const unsigned short* Wb = whh + ((long)(dir*768 + c)) * 256 + quad*8;
      #pragma unroll
      for (int kt = 0; kt < 8; kt++){
        wr[i][kt] = *(const bf16x8*)(Wb + kt*32);
        wz[i][kt] = *(const bf16x8*)(Wb + 256*256 + kt*32);
        asm volatile("" : "+v"(wr[i][kt]), "+v"(wz[i][kt]));
      }
    }

    float h_old[2][4];
    #pragma unroll
    for (int i = 0; i < 2; i++){
      int c = (wave*2 + i)*16 + ln16;
      #pragma unroll
      for (int r = 0; r < 4; r++){
        int b = quad*4 + r;
        float hv = hstate[((long)dir*256 + b0 + b)*256 + c];
        h_old[i][r] = hv;
        hbuf[b * 264 + c] = f2bf(hv);
      }
    }
    float bh_n[2];
    #pragma unroll
    for (int i = 0; i < 2; i++){
      int c = (wave*2 + i)*16 + ln16;
      bh_n[i] = bf2f(bhh[dir*768 + 512 + c]);
    }

    int wnb0 = ((wave*2 + 0)*8)*64*8 + lane*8;
    int wnb1 = ((wave*2 + 1)*8)*64*8 + lane*8;

    int tl = dir ? (CT-1) : 0;
    bf16x8 c_rz0 = *(const bf16x8*)(rzbase + (long)tl*RZ_TL);
    bf16x8 c_rz1 = *(const bf16x8*)(rzbase + (long)tl*RZ_TL + 8);
    bf16x8 c_n   = *(const bf16x8*)(nbase  + (long)tl*N_TL);
    __syncthreads();

    int p = 0;
    for (int ss = 0; ss < CT; ss++){
      int tln = (ss == CT-1) ? tl : (dir ? tl-1 : tl+1);

      unsigned short* hb_cur = hbuf + p*HBUF_SH;
      unsigned short* hb_nxt = hbuf + (1-p)*HBUF_SH;

      f32x4 ar[2], az[2], an[2];
      #pragma unroll
      for (int i = 0; i < 2; i++){
        ar[i] = (f32x4){0.f,0.f,0.f,0.f};
        az[i] = (f32x4){0.f,0.f,0.f,0.f};
        an[i] = (f32x4){0.f,0.f,0.f,0.f};
      }

      bf16x8 afb[2], wnb[2][2];
      afb[0]    = *(bf16x8*)&hb_cur[ln16*264 + quad*8];
      wnb[0][0] = *(bf16x8*)&wn_lds[wnb0];
      wnb[0][1] = *(bf16x8*)&wn_lds[wnb1];
      #pragma unroll
      for (int kt = 0; kt < 8; kt++){
        int cur = kt & 1, nxt = cur ^ 1;
        if (kt < 7){
          afb[nxt]    = *(bf16x8*)&hb_cur[ln16*264 + (kt+1)*32 + quad*8];
          wnb[nxt][0] = *(bf16x8*)&wn_lds[wnb0 + (kt+1)*64*8];
          wnb[nxt][1] = *(bf16x8*)&wn_lds[wnb1 + (kt+1)*64*8];
        }
        ar[0] = __builtin_amdgcn_mfma_f32_16x16x32_bf16(afb[cur], wr[0][kt], ar[0], 0, 0, 0);
        az[0] = __builtin_amdgcn_mfma_f32_16x16x32_bf16(afb[cur], wz[0][kt], az[0], 0, 0, 0);
        an[0] = __builtin_amdgcn_mfma_f32_16x16x32_bf16(afb[cur], wnb[cur][0], an[0], 0, 0, 0);
        ar[1] = __builtin_amdgcn_mfma_f32_16x16x32_bf16(afb[cur], wr[1][kt], ar[1], 0, 0, 0);
        az[1] = __builtin_amdgcn_mfma_f32_16x16x32_bf16(afb[cur], wz[1][kt], az[1], 0, 0, 0);
        an[1] = __builtin_amdgcn_mfma_f32_16x16x32_bf16(afb[cur], wnb[cur][1], an[1], 0, 0, 0);
      }

      bf16x8 n_rz0 = *(const bf16x8*)(rzbase + (long)tln*RZ_TL);
      bf16x8 n_rz1 = *(const bf16x8*)(rzbase + (long)tln*RZ_TL + 8);
      bf16x8 n_n   = *(const bf16x8*)(nbase  + (long)tln*N_TL);

      #pragma unroll
      for (int i = 0; i < 2; i++){
        int c = (wave*2 + i)*16 + ln16;
        #pragma unroll
        for (int r = 0; r < 4; r++){
          float xr = bf2f((unsigned short)(i ? c_rz1[r]   : c_rz0[r]));
          float xz = bf2f((unsigned short)(i ? c_rz1[4+r] : c_rz0[4+r]));
          float xn = bf2f((unsigned short)c_n[i*4 + r]);
          float rg = sigm(xr + ar[i][r]);
          float zg = sigm(xz + az[i][r]);
          float ng = tanh_f(xn + rg * (an[i][r] + bh_n[i]));
          float hnew = (1.f - zg) * ng + zg * h_old[i][r];
          h_old[i][r] = hnew;
          unsigned short hb = f2bf(hnew);
          int b = b0 + quad*4 + r;
          hb_nxt[(quad*4 + r) * 264 + c] = hb;
          long oidx = out_full ? (((long)(t0 + tl) * 256 + b) * 512 + dir*256 + c)
                               : (((long)tl * 256 + b) * 256 + c);
          outp[oidx] = hb;
        }
      }
      // LDS-only barrier (round-10 construct, proven safe + standalone-null):
      // under fused contention, stores stay in flight instead of draining per step.
      asm volatile("s_waitcnt lgkmcnt(0)\n\ts_barrier" ::: "memory");
      p ^= 1;
      tl = tln;
      c_rz0 = n_rz0; c_rz1 = n_rz1; c_n = n_n;
    }

    #pragma unroll
    for (int i = 0; i < 2; i++){
      int c = (wave*2 + i)*16 + ln16;
      #pragma unroll
      for (int r = 0; r < 4; r++)
        hstate[((long)dir*256 + b0 + quad*4 + r)*256 + c] = h_old[i][r];
    }
    return;
  }

  int gb = bid - (has_gru ? 32 : 0);

  // ---------------- GEMM role (two 128-wide n0 tiles per 512-thr block) ----------------
  if (gb < n_gemm){
    int half = tid >> 8, tq = tid & 255;
    int bx = gb & 63;               // m0 tile: CROWS/128 = 64
    int rest = gb >> 6;             // 0..5
    int by = rest % 3, gdir = rest / 3;
    const unsigned short* Ad = A + (long)(gdir ? g_t0b : g_t0f) * 256 * K;
    const unsigned short* Wd = W + (long)gdir * 768 * K;
    const unsigned short* bd = bias + gdir * 768;
    unsigned short* rzd = xprz_w + (long)gdir * RZ_DIR;
    unsigned short* nd  = xpn_w  + (long)gdir * N_DIR;
    unsigned short* As = smem;                       // 9216 shorts
    unsigned short* Bs = smem + 9216 + half*9216;    // per-half B tile

    long m0 = (long)bx * 128;
    int  n0 = (by*2 + half) * 128;
    int wave = tq >> 6, lane = tq & 63;
    int wm = (wave & 1) * 64, wn = (wave >> 1) * 64;
    int ln16 = lane & 15, quad = lane >> 4;
    f32x4 acc[4][4];
    #pragma unroll
    for (int i = 0; i < 4; i++)
      #pragma unroll
      for (int j = 0; j < 4; j++) acc[i][j] = (f32x4){0.f,0.f,0.f,0.f};

    for (int k0 = 0; k0 < K; k0 += 64){
      #pragma unroll
      for (int i = 0; i < 4; i++){
        int cc = tq + 256 * i;      // 1024 chunks of 8 bf16
        int row = cc >> 3, koff = (cc & 7) * 8;
        if (half == 0)
          *(bf16x8*)&As[row * 72 + koff] = *(const bf16x8*)&Ad[(m0 + row) * K + k0 + koff];
        *(bf16x8*)&Bs[row * 72 + koff] = *(const bf16x8*)&Wd[(long)(n0 + row) * K + k0 + koff];
      }
      __syncthreads();
      #pragma unroll
      for (int kk = 0; kk < 64; kk += 32){
        bf16x8 af[4], bfr[4];
        #pragma unroll
        for (int mi = 0; mi < 4; mi++) af[mi]  = *(bf16x8*)&As[(wm + mi*16 + ln16) * 72 + kk + quad*8];
        #pragma unroll
        for (int nj = 0; nj < 4; nj++) bfr[nj] = *(bf16x8*)&Bs[(wn + nj*16 + ln16) * 72 + kk + quad*8];
        #pragma unroll
        for (int mi = 0; mi < 4; mi++)
          #pragma unroll
          for (int nj = 0; nj < 4; nj++)
            acc[mi][nj] = __builtin_amdgcn_mfma_f32_16x16x32_bf16(af[mi], bfr[nj], acc[mi][nj], 0, 0, 0);
      }
      __syncthreads();
    }
    // swizzled epilogue
    #pragma unroll
    for (int mi = 0; mi < 4; mi++)
      #pragma unroll
      for (int nj = 0; nj < 4; nj++){
        int n = n0 + wn + nj*16 + ln16;       // 0..767 within dir
        int g = n >> 8, cc = n & 255;
        int w = cc >> 5, ii = (cc >> 4) & 1;
        float bv = bf2f(bd[n]);
        #pragma unroll
        for (int r = 0; r < 4; r++){
          long m = m0 + wm + mi*16 + quad*4 + r;
          int tl = (int)(m >> 8);
          int bgx = ((int)m & 255) >> 4;
          long rec = (((long)tl*16 + bgx)*8 + w)*64 + quad*16 + ln16;
          unsigned short val = f2bf(acc[mi][nj][r] + bv);
          if (g < 2) rzd[rec*16 + ii*8 + g*4 + r] = val;
          else       nd [rec*8  + ii*4 + r]       = val;
        }
      }
    return;
  }

  // ---------------- FC1 role (two (mb,kb,dir) units per 512-thr block) ----------------
  if (has_fc1){
    int fb = gb - n_gemm;           // 0..31
    if (fb >= 32) return;
    int half = tid >> 8, tq = tid & 255;
    int unit = fb*2 + half;         // 0..63
    int fdir = unit >> 5;
    int u = unit & 31;
    int mb = u & 3, kb = u >> 2;    // kb 0..7
    const unsigned short* h2d = h2r + (long)fdir * CROWS * 256;
    int t0 = fdir ? f_t0b : f_t0f;
    int dircol = fdir * 256;
    int wave = tq >> 6, lane = tq & 63;
    int ln16 = lane & 15, quad = lane >> 4;
    int w1fp32 = (int)*w1f;
    f32x4 acc[8];
    #pragma unroll
    for (int nt = 0; nt < 8; nt++) acc[nt] = (f32x4){0.f,0.f,0.f,0.f};

    for (int tt = 0; tt < 4; tt++){
      int tl = kb*4 + tt;           // 0..31
      const unsigned short* Ah = h2d + ((long)tl * 256 + mb*64 + wave*16) * 256;
      long bbase = (long)(t0 + tl) * 512 + dircol;
      #pragma unroll
      for (int kt = 0; kt < 8; kt++){
        bf16x8 af = *(const bf16x8*)(Ah + (long)ln16*256 + kt*32 + quad*8);
        #pragma unroll
        for (int nt = 0; nt < 8; nt++){
          long off = bbase + (long)(nt*16 + ln16)*262144 + kt*32 + quad*8;
          bf16x8 bfr;
          if (w1fp32){
            const float* pp = (const float*)W1 + off;
            #pragma unroll
            for (int j = 0; j < 8; j++) bfr[j] = (short)f2bf(pp[j]);
          } else {
            bfr = *(const bf16x8*)((const unsigned short*)W1 + off);
          }
          acc[nt] = __builtin_amdgcn_mfma_f32_16x16x32_bf16(af, bfr, acc[nt], 0, 0, 0);
        }
      }
    }
    #pragma unroll
    for (int nt = 0; nt < 8; nt++)
      #pragma unroll
      for (int r = 0; r < 4; r++){
        int m = mb*64 + wave*16 + quad*4 + r;
        int n = nt*16 + ln16;
        atomicAdd(&fc1acc[m*128 + n], acc[nt][r]);
      }
  }
}

// ------- final: leaky_relu(fc1acc + b1) @ W2 + b2 -> sigmoid -------
__global__ __launch_bounds__(256) void k_fc2(const float* __restrict__ fc1acc,
                                             const unsigned short* __restrict__ b1,
                                             const unsigned short* __restrict__ W2,
                                             const unsigned short* __restrict__ b2,
                                             const unsigned* __restrict__ flags,
                                             void* __restrict__ out){
  int b = threadIdx.x;
  float s = bf2f(b2[0]);
  for (int j = 0; j < 128; j++){
    float v = fc1acc[b*128 + j] + bf2f(b1[j]);
    v = v > 0.f ? v : 0.01f * v;
    s += v * bf2f(W2[j]);
  }
  float r = sigm(s);
  if (flags[1]) ((float*)out)[b] = r;          // fp32 world -> fp32 output
  else          ((unsigned short*)out)[b] = f2bf(r);
}

extern "C" void kernel_launch(void* const* d_in, const int* in_sizes, int n_in,
                              void* d_out, int out_size, void* d_ws, size_t ws_size,
                              hipStream_t stream) {
  const void* inp  = d_in[0];
  const void* emb  = d_in[1];
  const void* wih0 = d_in[2];
  const void* whh0 = d_in[3];
  const void* bih0 = d_in[4];
  const void* bhh0 = d_in[5];
  const void* wih1 = d_in[6];
  const void* whh1 = d_in[7];
  const void* bih1 = d_in[8];
  const void* bhh1 = d_in[9];
  const void* W1   = d_in[10];
  const void* b1   = d_in[11];
  const void* W2   = d_in[12];
  const void* b2   = d_in[13];
  unsigned short* out = (unsigned short*)d_out;

  const int expect[14] = {131072, 8320, 196608, 393216, 1536, 1536,
                          786432, 393216, 1536, 1536, 33554432, 128, 128, 1};
  for (int i = 0; i < 14 && i < n_in; i++){
    if (in_sizes[i] != expect[i]){
      k_sentinel<<<1, 256, 0, stream>>>(out, 4.0f * (600.0f + i));
      return;
    }
  }

  // dynamic LDS attr (idempotent host-side attr, not a stream op; 145 KB)
  static int smem_set = 0;
  if (!smem_set){
    hipFuncSetAttribute((const void*)k_fused,
                        hipFuncAttributeMaxDynamicSharedMemorySize, GRU_SMEM);
    smem_set = 1;
  }

  // workspace layout (bytes) -- total footprint IDENTICAL to previous rounds
  const size_t OFF_X    = 0;                       // x    [131072*128] bf16 (33.5 MB)
  const size_t OFF_H1   = 33554432ul;              // h1   [131072*512] bf16 (134 MB)
  const size_t OFF_XP   = 167772160ul;             // xp ping-pong: 2 sets x 25.2 MB
  const size_t OFF_H2   = 218103808ul;             // h2 ping-pong: 2 sets x 8.4 MB
  const size_t OFF_ST   = 234881024ul;             // hstate [2*256*256] f32
  const size_t OFF_FC   = 235405312ul;             // fc1acc [256*128] f32
  const size_t OFF_FLAG = 235536384ul;             // 16 flag words
  const size_t OFF_P    = 235536448ul;             // converted bf16 params (~3.6 MB)
  unsigned short* P;
  const size_t PO_EMB  = 0;        // 8320
  const size_t PO_WIH0 = 8320;     // 196608
  const size_t PO_WHH0 = 204928;   // 393216
  const size_t PO_BIH0 = 598144;   // 1536
  const size_t PO_BHH0 = 599680;   // 1536
  const size_t PO_WIH1 = 601216;   // 786432
  const size_t PO_WHH1 = 1387648;  // 393216
  const size_t PO_BIH1 = 1780864;  // 1536
  const size_t PO_BHH1 = 1782400;  // 1536
  const size_t PO_B1   = 1783936;  // 128
  const size_t PO_W2   = 1784064;  // 128
  const size_t PO_B2   = 1784192;  // 1 (+pad)
  const size_t PO_CB0  = 1784200;  // combined bias layer0 [2*768]
  const size_t PO_CB1  = 1785736;  // combined bias layer1 [2*768]
  const size_t NEED    = OFF_P + 2*(1785736ul + 1536ul);

  if (ws_size < NEED) {
    k_sentinel<<<1, 256, 0, stream>>>(out, (float)(ws_size >> 20));
    return;
  }

  char* ws = (char*)d_ws;
  unsigned short* x    = (unsigned short*)(ws + OFF_X);
  unsigned short* h1   = (unsigned short*)(ws + OFF_H1);
  float*          hst  = (float*)(ws + OFF_ST);
  float*          fc1a = (float*)(ws + OFF_FC);
  unsigned*       flg  = (unsigned*)(ws + OFF_FLAG);
  P = (unsigned short*)(ws + OFF_P);

  hipMemsetAsync(flg, 0, 64, stream);

  // ---- dtype probes ----
  k_probe_f<<<1,256,0,stream>>>((const unsigned short*)emb,  8320,     flg+1);
  k_probe_f<<<1,256,0,stream>>>((const unsigned short*)wih0, 196608,   flg+2);
  k_probe_f<<<1,256,0,stream>>>((const unsigned short*)whh0, 393216,   flg+3);
  k_probe_f<<<1,256,0,stream>>>((const unsigned short*)bih0, 1536,     flg+4);
  k_probe_f<<<1,256,0,stream>>>((const unsigned short*)bhh0, 1536,     flg+5);
  k_probe_f<<<1,256,0,stream>>>((const unsigned short*)wih1, 786432,   flg+6);
  k_probe_f<<<1,256,0,stream>>>((const unsigned short*)whh1, 393216,   flg+7);
  k_probe_f<<<1,256,0,stream>>>((const unsigned short*)bih1, 1536,     flg+8);
  k_probe_f<<<1,256,0,stream>>>((const unsigned short*)bhh1, 1536,     flg+9);
  k_probe_f<<<1,256,0,stream>>>((const unsigned short*)b1,   128,      flg+10);
  k_probe_f<<<1,256,0,stream>>>((const unsigned short*)W2,   128,      flg+11);
  k_probe_f<<<1,256,0,stream>>>((const unsigned short*)b2,   1,        flg+12);
  k_probe_f<<<1,256,0,stream>>>((const unsigned short*)W1,   33554432, flg+13);
  k_probe_i<<<1,256,0,stream>>>((const int*)inp, 131072, flg+14);

  // ---- convert params to bf16 ----
  k_convert<<<64,256,0,stream>>>(emb,  8320,   flg+1,  P+PO_EMB);
  k_convert<<<64,256,0,stream>>>(wih0, 196608, flg+2,  P+PO_WIH0);
  k_convert<<<64,256,0,stream>>>(whh0, 393216, flg+3,  P+PO_WHH0);
  k_convert<<<8, 256,0,stream>>>(bih0, 1536,   flg+4,  P+PO_BIH0);
  k_convert<<<8, 256,0,stream>>>(bhh0, 1536,   flg+5,  P+PO_BHH0);
  k_convert<<<64,256,0,stream>>>(wih1, 786432, flg+6,  P+PO_WIH1);
  k_convert<<<64,256,0,stream>>>(whh1, 393216, flg+7,  P+PO_WHH1);
  k_convert<<<8, 256,0,stream>>>(bih1, 1536,   flg+8,  P+PO_BIH1);
  k_convert<<<8, 256,0,stream>>>(bhh1, 1536,   flg+9,  P+PO_BHH1);
  k_convert<<<1, 256,0,stream>>>(b1,   128,    flg+10, P+PO_B1);
  k_convert<<<1, 256,0,stream>>>(W2,   128,    flg+11, P+PO_W2);
  k_convert<<<1, 256,0,stream>>>(b2,   1,      flg+12, P+PO_B2);

  // ---- combined biases (b_ih + b_hh for r,z gates) ----
  k_prep_bias<<<6,256,0,stream>>>(P+PO_BIH0, P+PO_BHH0, P+PO_CB0);
  k_prep_bias<<<6,256,0,stream>>>(P+PO_BIH1, P+PO_BHH1, P+PO_CB1);

  k_embed<<<MM*16/256, 256, 0, stream>>>(P+PO_EMB, inp, flg+14, x);

  // ---- layer 0: pipeline { gemm(c) } with { gru(c-1) } ----
  hipMemsetAsync(hst, 0, 2*256*256*sizeof(float), stream);
  for (int c = 0; c <= NCH; c++){
    int has_g = (c < NCH);
    int has_r = (c > 0);
    unsigned short* xprz_w = (unsigned short*)(ws + OFF_XP + (size_t)(c & 1)*XPSET_B);
    unsigned short* xpn_w  = (unsigned short*)(ws + OFF_XP + (size_t)(c & 1)*XPSET_B + XPN_OFF_B);
    unsigned short* xprz_r = (unsigned short*)(ws + OFF_XP + (size_t)((c-1) & 1)*XPSET_B);
    unsigned short* xpn_r  = (unsigned short*)(ws + OFF_XP + (size_t)((c-1) & 1)*XPSET_B + XPN_OFF_B);
    int gt0f = c*CT, gt0b = (NCH-1-c)*CT;
    int rt0f = (c-1)*CT, rt0b = (NCH-c)*CT;
    int n_gemm = has_g ? 384 : 0;
    int grid = (has_r ? 32 : 0) + n_gemm;
    k_fused<<<grid, 512, GRU_SMEM, stream>>>(
        x, P+PO_WIH0, P+PO_CB0, xprz_w, xpn_w, 128, gt0f, gt0b, n_gemm,
        xprz_r, xpn_r, P+PO_WHH0, P+PO_BHH0, hst, h1, h1, 1, rt0f, rt0b, has_r,
        (const unsigned short*)nullptr, (const void*)nullptr,
        (const unsigned*)nullptr, (float*)nullptr, 0, 0, 0);
  }

  // ---- layer 1: pipeline { gemm(c) } with { gru(c-1) } with { fc1(c-2) } ----
  hipMemsetAsync(hst, 0, 2*256*256*sizeof(float), stream);
  hipMemsetAsync(fc1a, 0, 256*128*sizeof(float), stream);
  for (int c = 0; c <= NCH+1; c++){
    int has_g = (c < NCH);
    int has_r = (c >= 1 && c <= NCH);
    int has_f = (c >= 2);
    unsigned short* xprz_w = (unsigned short*)(ws + OFF_XP + (size_t)(c & 1)*XPSET_B);
    unsigned short* xpn_w  = (unsigned short*)(ws + OFF_XP + (size_t)(c & 1)*XPSET_B + XPN_OFF_B);
    unsigned short* xprz_r = (unsigned short*)(ws + OFF_XP + (size_t)((c-1) & 1)*XPSET_B);
    unsigned short* xpn_r  = (unsigned short*)(ws + OFF_XP + (size_t)((c-1) & 1)*XPSET_B + XPN_OFF_B);
    unsigned short* h2w = (unsigned short*)(ws + OFF_H2 + (size_t)((c-1) & 1)*H2SET_B);
    unsigned short* h2r = (unsigned short*)(ws + OFF_H2 + (size_t)((c-2) & 1)*H2SET_B);
    int gt0f = c*CT, gt0b = (NCH-1-c)*CT;
    int rt0f = (c-1)*CT, rt0b = (NCH-c)*CT;
    int ft0f = (c-2)*CT, ft0b = (NCH+1-c)*CT;
    int n_gemm = has_g ? 384 : 0;
    int grid = (has_r ? 32 : 0) + n_gemm + (has_f ? 32 : 0);
    if (grid == 0) continue;
    k_fused<<<grid, 512, GRU_SMEM, stream>>>(
        h1, P+PO_WIH1, P+PO_CB1, xprz_w, xpn_w, 512, gt0f, gt0b, n_gemm,
        xprz_r, xpn_r, P+PO_WHH1, P+PO_BHH1, hst,
        h2w, h2w + (long)CROWS*256, 0, rt0f, rt0b, has_r,
        h2r, W1, flg+13, fc1a, ft0f, ft0b, has_f);
  }

  k_fc2<<<1, 256, 0, stream>>>(fc1a, P+PO_B1, P+PO_W2, P+PO_B2, flg, d_out);
}